// Round 1
// baseline (845.335 us; speedup 1.0000x reference)
//
#include <hip/hip_runtime.h>

#define N_NODES 50000
#define N_EDGES 800000
#define N_GRAPHS 1024
#define N_LAYERS 5
#define D_IN 32
#define D_HID 128

// ---------------- CSR build ----------------

__global__ void zero_int_kernel(int* __restrict__ p, int n) {
  int i = blockIdx.x * blockDim.x + threadIdx.x;
  if (i < n) p[i] = 0;
}

__global__ void degree_kernel(const int* __restrict__ dst, int* __restrict__ deg) {
  int e = blockIdx.x * blockDim.x + threadIdx.x;
  if (e < N_EDGES) atomicAdd(&deg[dst[e]], 1);
}

// single-block exclusive scan: off[0..n-1] = exclusive prefix of deg, off[n] = total
__global__ __launch_bounds__(1024) void scan_kernel(const int* __restrict__ deg,
                                                    int* __restrict__ off, int n) {
  __shared__ int wsum[16];
  __shared__ int carry;
  const int tid = threadIdx.x;
  const int lane = tid & 63;
  const int w = tid >> 6;
  if (tid == 0) carry = 0;
  __syncthreads();
  for (int base = 0; base < n; base += 1024) {
    int i = base + tid;
    int v = (i < n) ? deg[i] : 0;
    int x = v;  // inclusive wave scan
    #pragma unroll
    for (int s = 1; s < 64; s <<= 1) {
      int t = __shfl_up(x, s, 64);
      if (lane >= s) x += t;
    }
    if (lane == 63) wsum[w] = x;
    __syncthreads();
    if (tid == 0) {
      int acc = 0;
      #pragma unroll
      for (int j = 0; j < 16; ++j) { int t = wsum[j]; wsum[j] = acc; acc += t; }
    }
    __syncthreads();
    int exc = carry + wsum[w] + (x - v);
    if (i < n) off[i] = exc;
    __syncthreads();                       // all threads have read carry
    if (tid == 1023) carry += wsum[15] + x; // wsum[15]=prefix of waves 0..14, x=wave15 total
    __syncthreads();
  }
  if (tid == 0) off[n] = carry;
}

__global__ void copy_int_kernel(const int* __restrict__ a, int* __restrict__ b, int n) {
  int i = blockIdx.x * blockDim.x + threadIdx.x;
  if (i < n) b[i] = a[i];
}

__global__ void fill_csr_kernel(const int* __restrict__ src, const int* __restrict__ dst,
                                int* __restrict__ cursor, int* __restrict__ csr_src) {
  int e = blockIdx.x * blockDim.x + threadIdx.x;
  if (e < N_EDGES) {
    int d = dst[e];
    int pos = atomicAdd(&cursor[d], 1);
    csr_src[pos] = src[e];
  }
}

// goff[g] = lower_bound(batch, g); batch is sorted
__global__ void graph_off_kernel(const int* __restrict__ batch, int* __restrict__ goff) {
  int g = blockIdx.x * blockDim.x + threadIdx.x;
  if (g <= N_GRAPHS) {
    int lo = 0, hi = N_NODES;
    while (lo < hi) { int mid = (lo + hi) >> 1; if (batch[mid] < g) lo = mid + 1; else hi = mid; }
    goff[g] = lo;
  }
}

// ---------------- compute ----------------

// h0 = x @ W_embed ; block = 2 nodes x 128 cols
__global__ __launch_bounds__(256) void embed_kernel(const float* __restrict__ x,
                                                    const float* __restrict__ W,
                                                    float* __restrict__ h) {
  __shared__ float Wl[D_IN * D_HID];  // 16 KB
  for (int i = threadIdx.x; i < D_IN * D_HID; i += 256) Wl[i] = W[i];
  __syncthreads();
  int node = blockIdx.x * 2 + (threadIdx.x >> 7);
  int d = threadIdx.x & 127;
  if (node < N_NODES) {
    const float* xr = x + (size_t)node * D_IN;
    float s = 0.f;
    #pragma unroll
    for (int k = 0; k < D_IN; ++k) s += xr[k] * Wl[k * D_HID + d];
    h[(size_t)node * D_HID + d] = s;
  }
}

// neigh[n,:] = sum over CSR row n of h[src,:] ; one wave per node, float2/lane
__global__ __launch_bounds__(256) void gather_kernel(const float* __restrict__ h,
                                                     const int* __restrict__ off,
                                                     const int* __restrict__ csr,
                                                     float* __restrict__ neigh) {
  int node = (blockIdx.x * blockDim.x + threadIdx.x) >> 6;
  int lane = threadIdx.x & 63;
  if (node >= N_NODES) return;
  int e0 = off[node], e1 = off[node + 1];
  float sx = 0.f, sy = 0.f;
  int e = e0;
  for (; e + 1 < e1; e += 2) {
    int j0 = __builtin_amdgcn_readfirstlane(csr[e]);
    int j1 = __builtin_amdgcn_readfirstlane(csr[e + 1]);
    float2 v0 = *reinterpret_cast<const float2*>(h + (size_t)j0 * D_HID + lane * 2);
    float2 v1 = *reinterpret_cast<const float2*>(h + (size_t)j1 * D_HID + lane * 2);
    sx += v0.x + v1.x; sy += v0.y + v1.y;
  }
  if (e < e1) {
    int j0 = __builtin_amdgcn_readfirstlane(csr[e]);
    float2 v0 = *reinterpret_cast<const float2*>(h + (size_t)j0 * D_HID + lane * 2);
    sx += v0.x; sy += v0.y;
  }
  float2 o; o.x = sx; o.y = sy;
  *reinterpret_cast<float2*>(neigh + (size_t)node * D_HID + lane * 2) = o;
}

// hout = (neigh + 2h) @ W + b ; W in LDS; 32 nodes/chunk; thread = 4 nodes x 4 cols
__global__ __launch_bounds__(256) void gin_gemm_kernel(const float* __restrict__ neigh,
                                                       const float* __restrict__ h,
                                                       const float* __restrict__ W,
                                                       const float* __restrict__ b,
                                                       float* __restrict__ hout,
                                                       int numChunks) {
  __shared__ float Wlds[D_HID * D_HID];  // 64 KB
  __shared__ float arow[32][D_HID];      // 16 KB
  for (int i = threadIdx.x; i < D_HID * D_HID; i += 256) Wlds[i] = W[i];
  const int cg = threadIdx.x >> 5;          // 0..7
  const int d0 = (threadIdx.x & 31) << 2;   // column group
  const float4 bias = *reinterpret_cast<const float4*>(b + d0);
  for (int chunk = blockIdx.x; chunk < numChunks; chunk += gridDim.x) {
    int nodeBase = chunk * 32;
    __syncthreads();  // protects Wlds (first iter) and arow (later iters)
    for (int i = threadIdx.x; i < 32 * D_HID; i += 256) {
      int jj = i >> 7, k = i & 127;
      int nn = nodeBase + jj;
      float val = 0.f;
      if (nn < N_NODES)
        val = neigh[(size_t)nn * D_HID + k] + 2.0f * h[(size_t)nn * D_HID + k];
      arow[jj][k] = val;
    }
    __syncthreads();
    float4 a0 = {0,0,0,0}, a1 = {0,0,0,0}, a2 = {0,0,0,0}, a3 = {0,0,0,0};
    for (int k = 0; k < D_HID; ++k) {
      float4 w4 = *reinterpret_cast<const float4*>(&Wlds[k * D_HID + d0]);
      float v0 = arow[cg][k], v1 = arow[cg + 8][k], v2 = arow[cg + 16][k], v3 = arow[cg + 24][k];
      a0.x += v0 * w4.x; a0.y += v0 * w4.y; a0.z += v0 * w4.z; a0.w += v0 * w4.w;
      a1.x += v1 * w4.x; a1.y += v1 * w4.y; a1.z += v1 * w4.z; a1.w += v1 * w4.w;
      a2.x += v2 * w4.x; a2.y += v2 * w4.y; a2.z += v2 * w4.z; a2.w += v2 * w4.w;
      a3.x += v3 * w4.x; a3.y += v3 * w4.y; a3.z += v3 * w4.z; a3.w += v3 * w4.w;
    }
    #pragma unroll
    for (int r = 0; r < 4; ++r) {
      int node = nodeBase + cg + r * 8;
      if (node < N_NODES) {
        float4 acc = (r == 0) ? a0 : (r == 1) ? a1 : (r == 2) ? a2 : a3;
        float4 o;
        o.x = acc.x + bias.x; o.y = acc.y + bias.y;
        o.z = acc.z + bias.z; o.w = acc.w + bias.w;
        *reinterpret_cast<float4*>(&hout[(size_t)node * D_HID + d0]) = o;
      }
    }
  }
}

// out[g, layer*128 + d] = sum over nodes in graph g of h[n, d]
__global__ __launch_bounds__(128) void pool_kernel(const float* __restrict__ h,
                                                   const int* __restrict__ goff,
                                                   float* __restrict__ out, int layer) {
  int g = blockIdx.x;
  int d = threadIdx.x;
  int n0 = goff[g], n1 = goff[g + 1];
  float s = 0.f;
  for (int n = n0; n < n1; ++n) s += h[(size_t)n * D_HID + d];
  out[(size_t)g * ((N_LAYERS + 1) * D_HID) + layer * D_HID + d] = s;
}

// ---------------- launch ----------------

extern "C" void kernel_launch(void* const* d_in, const int* in_sizes, int n_in,
                              void* d_out, int out_size, void* d_ws, size_t ws_size,
                              hipStream_t stream) {
  const float* x       = (const float*)d_in[0];
  const int*   edges   = (const int*)d_in[1];
  const int*   src     = edges;
  const int*   dst     = edges + N_EDGES;
  const int*   batch   = (const int*)d_in[2];
  const float* W_embed = (const float*)d_in[3];
  const float* Ws      = (const float*)d_in[4];
  const float* bs      = (const float*)d_in[5];
  float* out = (float*)d_out;

  float* h0    = (float*)d_ws;                          // 50000*128 f32
  float* h1    = h0 + (size_t)N_NODES * D_HID;          // 50000*128 f32
  float* neigh = h1 + (size_t)N_NODES * D_HID;          // 50000*128 f32
  int*   off    = (int*)(neigh + (size_t)N_NODES * D_HID); // N+1
  int*   cursor = off + (N_NODES + 1);                     // N
  int*   csr    = cursor + N_NODES;                        // E
  int*   goff   = csr + N_EDGES;                           // G+1

  // CSR build (edge list is layer-invariant)
  zero_int_kernel<<<(N_NODES + 255) / 256, 256, 0, stream>>>(cursor, N_NODES);
  degree_kernel<<<(N_EDGES + 255) / 256, 256, 0, stream>>>(dst, cursor);
  scan_kernel<<<1, 1024, 0, stream>>>(cursor, off, N_NODES);
  copy_int_kernel<<<(N_NODES + 255) / 256, 256, 0, stream>>>(off, cursor, N_NODES);
  fill_csr_kernel<<<(N_EDGES + 255) / 256, 256, 0, stream>>>(src, dst, cursor, csr);
  graph_off_kernel<<<(N_GRAPHS + 1 + 255) / 256, 256, 0, stream>>>(batch, goff);

  // embedding + pool of feature 0
  embed_kernel<<<(N_NODES + 1) / 2, 256, 0, stream>>>(x, W_embed, h0);
  pool_kernel<<<N_GRAPHS, 128, 0, stream>>>(h0, goff, out, 0);

  const int numChunks = (N_NODES + 31) / 32;
  float* hc = h0;
  float* hn = h1;
  for (int l = 0; l < N_LAYERS; ++l) {
    gather_kernel<<<(N_NODES * 64 + 255) / 256, 256, 0, stream>>>(hc, off, csr, neigh);
    gin_gemm_kernel<<<512, 256, 0, stream>>>(neigh, hc,
                                             Ws + (size_t)l * D_HID * D_HID,
                                             bs + (size_t)l * D_HID, hn, numChunks);
    pool_kernel<<<N_GRAPHS, 128, 0, stream>>>(hn, goff, out, l + 1);
    float* t = hc; hc = hn; hn = t;
  }
}

// Round 3
// 682.841 us; speedup vs baseline: 1.2380x; 1.2380x over previous
//
#include <hip/hip_runtime.h>

#define N_NODES 50000
#define N_EDGES 800000
#define N_GRAPHS 1024
#define N_LAYERS 5
#define D_IN 32
#define D_HID 128

// ---------------- CSR build ----------------

__global__ void zero_int_kernel(int* __restrict__ p, int n) {
  int i = blockIdx.x * blockDim.x + threadIdx.x;
  if (i < n) p[i] = 0;
}

__global__ void degree_kernel(const int* __restrict__ dst, int* __restrict__ deg) {
  int e = blockIdx.x * blockDim.x + threadIdx.x;
  if (e < N_EDGES) atomicAdd(&deg[dst[e]], 1);
}

// single-block exclusive scan: off[0..n-1] = exclusive prefix of deg, off[n] = total
__global__ __launch_bounds__(1024) void scan_kernel(const int* __restrict__ deg,
                                                    int* __restrict__ off, int n) {
  __shared__ int wsum[16];
  __shared__ int carry;
  const int tid = threadIdx.x;
  const int lane = tid & 63;
  const int w = tid >> 6;
  if (tid == 0) carry = 0;
  __syncthreads();
  for (int base = 0; base < n; base += 1024) {
    int i = base + tid;
    int v = (i < n) ? deg[i] : 0;
    int x = v;  // inclusive wave scan
    #pragma unroll
    for (int s = 1; s < 64; s <<= 1) {
      int t = __shfl_up(x, s, 64);
      if (lane >= s) x += t;
    }
    if (lane == 63) wsum[w] = x;
    __syncthreads();
    if (tid == 0) {
      int acc = 0;
      #pragma unroll
      for (int j = 0; j < 16; ++j) { int t = wsum[j]; wsum[j] = acc; acc += t; }
    }
    __syncthreads();
    int exc = carry + wsum[w] + (x - v);
    if (i < n) off[i] = exc;
    __syncthreads();                        // all threads have read carry
    if (tid == 1023) carry += wsum[15] + x; // wsum[15]=prefix of waves 0..14, x=wave15 total
    __syncthreads();
  }
  if (tid == 0) off[n] = carry;
}

__global__ void copy_int_kernel(const int* __restrict__ a, int* __restrict__ b, int n) {
  int i = blockIdx.x * blockDim.x + threadIdx.x;
  if (i < n) b[i] = a[i];
}

__global__ void fill_csr_kernel(const int* __restrict__ src, const int* __restrict__ dst,
                                int* __restrict__ cursor, int* __restrict__ csr_src) {
  int e = blockIdx.x * blockDim.x + threadIdx.x;
  if (e < N_EDGES) {
    int d = dst[e];
    int pos = atomicAdd(&cursor[d], 1);
    csr_src[pos] = src[e];
  }
}

// goff[g] = lower_bound(batch, g); batch is sorted
__global__ void graph_off_kernel(const int* __restrict__ batch, int* __restrict__ goff) {
  int g = blockIdx.x * blockDim.x + threadIdx.x;
  if (g <= N_GRAPHS) {
    int lo = 0, hi = N_NODES;
    while (lo < hi) { int mid = (lo + hi) >> 1; if (batch[mid] < g) lo = mid + 1; else hi = mid; }
    goff[g] = lo;
  }
}

// ---------------- compute ----------------

// h0 = x @ W_embed ; block = 64 nodes, W + x-chunk staged in LDS
__global__ __launch_bounds__(256) void embed_kernel(const float* __restrict__ x,
                                                    const float* __restrict__ W,
                                                    float* __restrict__ h) {
  __shared__ float Wl[D_IN * D_HID];  // 16 KB
  __shared__ float xl[64 * D_IN];     // 8 KB
  for (int i = threadIdx.x; i < D_IN * D_HID; i += 256) Wl[i] = W[i];
  const int base = blockIdx.x * 64;
  const int nThis = (base + 64 <= N_NODES) ? 64 : (N_NODES - base);
  const float4* x4 = reinterpret_cast<const float4*>(x + (size_t)base * D_IN);
  for (int i = threadIdx.x; i < nThis * (D_IN / 4); i += 256)
    reinterpret_cast<float4*>(xl)[i] = x4[i];
  __syncthreads();
  const int sub = threadIdx.x >> 7;  // 0..1
  const int d = threadIdx.x & 127;
  for (int r = sub; r < nThis; r += 2) {
    float s = 0.f;
    #pragma unroll
    for (int k = 0; k < D_IN; ++k) s += xl[r * D_IN + k] * Wl[k * D_HID + d];
    h[(size_t)(base + r) * D_HID + d] = s;
  }
}

// agg[n,:] = sum_{j in N(n)} h[j,:] + 2*h[n,:]
// one wave per node; 64 edge indices preloaded coalesced, broadcast via shfl
__global__ __launch_bounds__(256) void gather_kernel(const float* __restrict__ h,
                                                     const int* __restrict__ off,
                                                     const int* __restrict__ csr,
                                                     float* __restrict__ agg) {
  const int node = (blockIdx.x * blockDim.x + threadIdx.x) >> 6;
  const int lane = threadIdx.x & 63;
  if (node >= N_NODES) return;
  const float2 self = *reinterpret_cast<const float2*>(h + (size_t)node * D_HID + lane * 2);
  float sx0 = 2.f * self.x, sy0 = 2.f * self.y, sx1 = 0.f, sy1 = 0.f;
  const int e0 = off[node], e1 = off[node + 1];
  for (int base = e0; base < e1; base += 64) {
    int cnt = e1 - base; if (cnt > 64) cnt = 64;
    int vidx = (base + lane < e1) ? csr[base + lane] : 0;
    int j = 0;
    for (; j + 4 <= cnt; j += 4) {
      int i0 = __shfl(vidx, j, 64);
      int i1 = __shfl(vidx, j + 1, 64);
      int i2 = __shfl(vidx, j + 2, 64);
      int i3 = __shfl(vidx, j + 3, 64);
      float2 v0 = *reinterpret_cast<const float2*>(h + (size_t)i0 * D_HID + lane * 2);
      float2 v1 = *reinterpret_cast<const float2*>(h + (size_t)i1 * D_HID + lane * 2);
      float2 v2 = *reinterpret_cast<const float2*>(h + (size_t)i2 * D_HID + lane * 2);
      float2 v3 = *reinterpret_cast<const float2*>(h + (size_t)i3 * D_HID + lane * 2);
      sx0 += v0.x + v1.x; sy0 += v0.y + v1.y;
      sx1 += v2.x + v3.x; sy1 += v2.y + v3.y;
    }
    for (; j < cnt; ++j) {
      int i0 = __shfl(vidx, j, 64);
      float2 v0 = *reinterpret_cast<const float2*>(h + (size_t)i0 * D_HID + lane * 2);
      sx0 += v0.x; sy0 += v0.y;
    }
  }
  float2 o; o.x = sx0 + sx1; o.y = sy0 + sy1;
  *reinterpret_cast<float2*>(agg + (size_t)node * D_HID + lane * 2) = o;
}

// hout = agg @ W + b ; W in LDS; 32 nodes/chunk; thread = 4 nodes x 4 cols,
// k register-blocked by 4 (8 ds_read_b128 per 64 FMA)
__global__ __launch_bounds__(256) void gin_gemm_kernel(const float* __restrict__ agg,
                                                       const float* __restrict__ W,
                                                       const float* __restrict__ b,
                                                       float* __restrict__ hout,
                                                       int numChunks) {
  __shared__ float Wlds[D_HID * D_HID];  // 64 KB
  __shared__ float arow[32 * D_HID];     // 16 KB
  for (int i = threadIdx.x; i < D_HID * D_HID; i += 256) Wlds[i] = W[i];
  const int cg = threadIdx.x >> 5;          // 0..7
  const int d0 = (threadIdx.x & 31) << 2;   // column group
  const float4 bias = *reinterpret_cast<const float4*>(b + d0);
  for (int chunk = blockIdx.x; chunk < numChunks; chunk += gridDim.x) {
    const int nodeBase = chunk * 32;
    __syncthreads();  // protects Wlds (first iter) and arow reuse (later iters)
    for (int i = threadIdx.x; i < 32 * (D_HID / 4); i += 256) {
      const int nn = nodeBase + (i >> 5);
      float4 v = {0.f, 0.f, 0.f, 0.f};
      if (nn < N_NODES)
        v = *reinterpret_cast<const float4*>(agg + (size_t)nn * D_HID + (size_t)(i & 31) * 4);
      reinterpret_cast<float4*>(arow)[i] = v;
    }
    __syncthreads();
    float4 a0 = {0,0,0,0}, a1 = {0,0,0,0}, a2 = {0,0,0,0}, a3 = {0,0,0,0};
    #pragma unroll 2
    for (int k4 = 0; k4 < 32; ++k4) {
      const int k = k4 * 4;
      const float4 w0 = *reinterpret_cast<const float4*>(&Wlds[(k + 0) * D_HID + d0]);
      const float4 w1 = *reinterpret_cast<const float4*>(&Wlds[(k + 1) * D_HID + d0]);
      const float4 w2 = *reinterpret_cast<const float4*>(&Wlds[(k + 2) * D_HID + d0]);
      const float4 w3 = *reinterpret_cast<const float4*>(&Wlds[(k + 3) * D_HID + d0]);
      const float4 va = *reinterpret_cast<const float4*>(&arow[(cg +  0) * D_HID + k]);
      const float4 vb = *reinterpret_cast<const float4*>(&arow[(cg +  8) * D_HID + k]);
      const float4 vc = *reinterpret_cast<const float4*>(&arow[(cg + 16) * D_HID + k]);
      const float4 vd = *reinterpret_cast<const float4*>(&arow[(cg + 24) * D_HID + k]);
      a0.x += va.x*w0.x + va.y*w1.x + va.z*w2.x + va.w*w3.x;
      a0.y += va.x*w0.y + va.y*w1.y + va.z*w2.y + va.w*w3.y;
      a0.z += va.x*w0.z + va.y*w1.z + va.z*w2.z + va.w*w3.z;
      a0.w += va.x*w0.w + va.y*w1.w + va.z*w2.w + va.w*w3.w;
      a1.x += vb.x*w0.x + vb.y*w1.x + vb.z*w2.x + vb.w*w3.x;
      a1.y += vb.x*w0.y + vb.y*w1.y + vb.z*w2.y + vb.w*w3.y;
      a1.z += vb.x*w0.z + vb.y*w1.z + vb.z*w2.z + vb.w*w3.z;
      a1.w += vb.x*w0.w + vb.y*w1.w + vb.z*w2.w + vb.w*w3.w;
      a2.x += vc.x*w0.x + vc.y*w1.x + vc.z*w2.x + vc.w*w3.x;
      a2.y += vc.x*w0.y + vc.y*w1.y + vc.z*w2.y + vc.w*w3.y;
      a2.z += vc.x*w0.z + vc.y*w1.z + vc.z*w2.z + vc.w*w3.z;
      a2.w += vc.x*w0.w + vc.y*w1.w + vc.z*w2.w + vc.w*w3.w;
      a3.x += vd.x*w0.x + vd.y*w1.x + vd.z*w2.x + vd.w*w3.x;
      a3.y += vd.x*w0.y + vd.y*w1.y + vd.z*w2.y + vd.w*w3.y;
      a3.z += vd.x*w0.z + vd.y*w1.z + vd.z*w2.z + vd.w*w3.z;
      a3.w += vd.x*w0.w + vd.y*w1.w + vd.z*w2.w + vd.w*w3.w;
    }
    #pragma unroll
    for (int r = 0; r < 4; ++r) {
      const int node = nodeBase + cg + r * 8;
      if (node < N_NODES) {
        float4 acc = (r == 0) ? a0 : (r == 1) ? a1 : (r == 2) ? a2 : a3;
        float4 o;
        o.x = acc.x + bias.x; o.y = acc.y + bias.y;
        o.z = acc.z + bias.z; o.w = acc.w + bias.w;
        *reinterpret_cast<float4*>(&hout[(size_t)node * D_HID + d0]) = o;
      }
    }
  }
}

// out[g, layer*128 + 4c..4c+3] = sum over nodes in graph g of h[n, 4c..4c+3]
// 32 threads per graph (32 x float4 = 128 cols), 8 graphs per 256-thread block
__global__ __launch_bounds__(256) void pool_kernel(const float* __restrict__ h,
                                                   const int* __restrict__ goff,
                                                   float* __restrict__ out, int layer) {
  const int g = blockIdx.x * 8 + (threadIdx.x >> 5);
  const int t = threadIdx.x & 31;   // column group: cols 4t..4t+3
  if (g >= N_GRAPHS) return;
  const int n0 = goff[g], n1 = goff[g + 1];
  float4 s = {0.f, 0.f, 0.f, 0.f};
  int n = n0;
  for (; n + 1 < n1; n += 2) {
    float4 v = *reinterpret_cast<const float4*>(h + (size_t)n * D_HID + t * 4);
    float4 w = *reinterpret_cast<const float4*>(h + (size_t)(n + 1) * D_HID + t * 4);
    s.x += v.x + w.x; s.y += v.y + w.y; s.z += v.z + w.z; s.w += v.w + w.w;
  }
  if (n < n1) {
    float4 v = *reinterpret_cast<const float4*>(h + (size_t)n * D_HID + t * 4);
    s.x += v.x; s.y += v.y; s.z += v.z; s.w += v.w;
  }
  *reinterpret_cast<float4*>(out + (size_t)g * ((N_LAYERS + 1) * D_HID) + layer * D_HID + t * 4) = s;
}

// ---------------- launch ----------------

extern "C" void kernel_launch(void* const* d_in, const int* in_sizes, int n_in,
                              void* d_out, int out_size, void* d_ws, size_t ws_size,
                              hipStream_t stream) {
  const float* x       = (const float*)d_in[0];
  const int*   edges   = (const int*)d_in[1];
  const int*   src     = edges;
  const int*   dst     = edges + N_EDGES;
  const int*   batch   = (const int*)d_in[2];
  const float* W_embed = (const float*)d_in[3];
  const float* Ws      = (const float*)d_in[4];
  const float* bs      = (const float*)d_in[5];
  float* out = (float*)d_out;

  float* h0    = (float*)d_ws;                          // 50000*128 f32
  float* h1    = h0 + (size_t)N_NODES * D_HID;          // 50000*128 f32
  float* agg   = h1 + (size_t)N_NODES * D_HID;          // 50000*128 f32
  int*   off    = (int*)(agg + (size_t)N_NODES * D_HID);   // N+1
  int*   cursor = off + (N_NODES + 1);                     // N
  int*   csr    = cursor + N_NODES;                        // E
  int*   goff   = csr + N_EDGES;                           // G+1

  // CSR build (edge list is layer-invariant)
  zero_int_kernel<<<(N_NODES + 255) / 256, 256, 0, stream>>>(cursor, N_NODES);
  degree_kernel<<<(N_EDGES + 255) / 256, 256, 0, stream>>>(dst, cursor);
  scan_kernel<<<1, 1024, 0, stream>>>(cursor, off, N_NODES);
  copy_int_kernel<<<(N_NODES + 255) / 256, 256, 0, stream>>>(off, cursor, N_NODES);
  fill_csr_kernel<<<(N_EDGES + 255) / 256, 256, 0, stream>>>(src, dst, cursor, csr);
  graph_off_kernel<<<(N_GRAPHS + 1 + 255) / 256, 256, 0, stream>>>(batch, goff);

  // embedding + pool of feature 0
  embed_kernel<<<(N_NODES + 63) / 64, 256, 0, stream>>>(x, W_embed, h0);
  pool_kernel<<<N_GRAPHS / 8, 256, 0, stream>>>(h0, goff, out, 0);

  const int numChunks = (N_NODES + 31) / 32;
  float* hc = h0;
  float* hn = h1;
  for (int l = 0; l < N_LAYERS; ++l) {
    gather_kernel<<<(N_NODES * 64 + 255) / 256, 256, 0, stream>>>(hc, off, csr, agg);
    gin_gemm_kernel<<<512, 256, 0, stream>>>(agg,
                                             Ws + (size_t)l * D_HID * D_HID,
                                             bs + (size_t)l * D_HID, hn, numChunks);
    pool_kernel<<<N_GRAPHS / 8, 256, 0, stream>>>(hn, goff, out, l + 1);
    float* t = hc; hc = hn; hn = t;
  }
}

// Round 4
// 579.198 us; speedup vs baseline: 1.4595x; 1.1789x over previous
//
#include <hip/hip_runtime.h>

#define N_NODES 50000
#define N_EDGES 800000
#define N_GRAPHS 1024
#define N_LAYERS 5
#define D_IN 32
#define D_HID 128

// ---------------- bf16 helpers (h is stored as bf16 to halve fabric traffic) ----

__device__ __forceinline__ float bf_lo(unsigned u) { return __uint_as_float(u << 16); }
__device__ __forceinline__ float bf_hi(unsigned u) { return __uint_as_float(u & 0xffff0000u); }
__device__ __forceinline__ unsigned bf16_rn(float f) {
  unsigned u = __float_as_uint(f);
  return (u + 0x7fffu + ((u >> 16) & 1u)) >> 16;  // round-to-nearest-even
}
__device__ __forceinline__ unsigned pack_bf16(float a, float b) {
  return bf16_rn(a) | (bf16_rn(b) << 16);
}

// ---------------- CSR build ----------------

__global__ void zero_int_kernel(int* __restrict__ p, int n) {
  int i = blockIdx.x * blockDim.x + threadIdx.x;
  if (i < n) p[i] = 0;
}

__global__ void degree_kernel(const int* __restrict__ dst, int* __restrict__ deg) {
  int e = blockIdx.x * blockDim.x + threadIdx.x;
  if (e < N_EDGES) atomicAdd(&deg[dst[e]], 1);
}

// single-block exclusive scan: off[0..n-1] = exclusive prefix of deg, off[n] = total
__global__ __launch_bounds__(1024) void scan_kernel(const int* __restrict__ deg,
                                                    int* __restrict__ off, int n) {
  __shared__ int wsum[16];
  __shared__ int carry;
  const int tid = threadIdx.x;
  const int lane = tid & 63;
  const int w = tid >> 6;
  if (tid == 0) carry = 0;
  __syncthreads();
  for (int base = 0; base < n; base += 1024) {
    int i = base + tid;
    int v = (i < n) ? deg[i] : 0;
    int x = v;  // inclusive wave scan
    #pragma unroll
    for (int s = 1; s < 64; s <<= 1) {
      int t = __shfl_up(x, s, 64);
      if (lane >= s) x += t;
    }
    if (lane == 63) wsum[w] = x;
    __syncthreads();
    if (tid == 0) {
      int acc = 0;
      #pragma unroll
      for (int j = 0; j < 16; ++j) { int t = wsum[j]; wsum[j] = acc; acc += t; }
    }
    __syncthreads();
    int exc = carry + wsum[w] + (x - v);
    if (i < n) off[i] = exc;
    __syncthreads();                        // all threads have read carry
    if (tid == 1023) carry += wsum[15] + x; // wsum[15]=prefix of waves 0..14, x=wave15 total
    __syncthreads();
  }
  if (tid == 0) off[n] = carry;
}

__global__ void copy_int_kernel(const int* __restrict__ a, int* __restrict__ b, int n) {
  int i = blockIdx.x * blockDim.x + threadIdx.x;
  if (i < n) b[i] = a[i];
}

__global__ void fill_csr_kernel(const int* __restrict__ src, const int* __restrict__ dst,
                                int* __restrict__ cursor, int* __restrict__ csr_src) {
  int e = blockIdx.x * blockDim.x + threadIdx.x;
  if (e < N_EDGES) {
    int d = dst[e];
    int pos = atomicAdd(&cursor[d], 1);
    csr_src[pos] = src[e];
  }
}

// goff[g] = lower_bound(batch, g); batch is sorted
__global__ void graph_off_kernel(const int* __restrict__ batch, int* __restrict__ goff) {
  int g = blockIdx.x * blockDim.x + threadIdx.x;
  if (g <= N_GRAPHS) {
    int lo = 0, hi = N_NODES;
    while (lo < hi) { int mid = (lo + hi) >> 1; if (batch[mid] < g) lo = mid + 1; else hi = mid; }
    goff[g] = lo;
  }
}

// ---------------- compute ----------------

// hb = bf16(x @ W_embed) ; block = 64 nodes; thread computes 2 adjacent cols
__global__ __launch_bounds__(256) void embed_kernel(const float* __restrict__ x,
                                                    const float* __restrict__ W,
                                                    unsigned short* __restrict__ hb) {
  __shared__ float Wl[D_IN * D_HID];  // 16 KB
  __shared__ float xl[64 * D_IN];     // 8 KB
  for (int i = threadIdx.x; i < D_IN * D_HID; i += 256) Wl[i] = W[i];
  const int base = blockIdx.x * 64;
  const int nThis = (base + 64 <= N_NODES) ? 64 : (N_NODES - base);
  const float4* x4 = reinterpret_cast<const float4*>(x + (size_t)base * D_IN);
  for (int i = threadIdx.x; i < nThis * (D_IN / 4); i += 256)
    reinterpret_cast<float4*>(xl)[i] = x4[i];
  __syncthreads();
  const int c2 = (threadIdx.x & 63) * 2;   // cols c2, c2+1
  const int sub = threadIdx.x >> 6;        // 0..3
  for (int r = sub; r < nThis; r += 4) {
    float s0 = 0.f, s1 = 0.f;
    #pragma unroll
    for (int k = 0; k < D_IN; ++k) {
      float xv = xl[r * D_IN + k];
      s0 += xv * Wl[k * D_HID + c2];
      s1 += xv * Wl[k * D_HID + c2 + 1];
    }
    *reinterpret_cast<unsigned*>(hb + (size_t)(base + r) * D_HID + c2) = pack_bf16(s0, s1);
  }
}

// agg[n,:] = sum_{j in N(n)} h[j,:] + 2*h[n,:]  (h read as bf16, accum f32)
// one wave per node; 64 edge indices preloaded coalesced, broadcast via shfl;
// each row is one 256B load instruction (64 lanes x 4B)
__global__ __launch_bounds__(256) void gather_kernel(const unsigned short* __restrict__ hb,
                                                     const int* __restrict__ off,
                                                     const int* __restrict__ csr,
                                                     float* __restrict__ agg) {
  const int node = (blockIdx.x * blockDim.x + threadIdx.x) >> 6;
  const int lane = threadIdx.x & 63;
  if (node >= N_NODES) return;
  const unsigned su = *reinterpret_cast<const unsigned*>(hb + (size_t)node * D_HID + lane * 2);
  float sx0 = 2.f * bf_lo(su), sy0 = 2.f * bf_hi(su), sx1 = 0.f, sy1 = 0.f;
  const int e0 = off[node], e1 = off[node + 1];
  for (int base = e0; base < e1; base += 64) {
    int cnt = e1 - base; if (cnt > 64) cnt = 64;
    int vidx = (base + lane < e1) ? csr[base + lane] : 0;
    int j = 0;
    for (; j + 4 <= cnt; j += 4) {
      int i0 = __shfl(vidx, j, 64);
      int i1 = __shfl(vidx, j + 1, 64);
      int i2 = __shfl(vidx, j + 2, 64);
      int i3 = __shfl(vidx, j + 3, 64);
      unsigned u0 = *reinterpret_cast<const unsigned*>(hb + (size_t)i0 * D_HID + lane * 2);
      unsigned u1 = *reinterpret_cast<const unsigned*>(hb + (size_t)i1 * D_HID + lane * 2);
      unsigned u2 = *reinterpret_cast<const unsigned*>(hb + (size_t)i2 * D_HID + lane * 2);
      unsigned u3 = *reinterpret_cast<const unsigned*>(hb + (size_t)i3 * D_HID + lane * 2);
      sx0 += bf_lo(u0) + bf_lo(u1); sy0 += bf_hi(u0) + bf_hi(u1);
      sx1 += bf_lo(u2) + bf_lo(u3); sy1 += bf_hi(u2) + bf_hi(u3);
    }
    for (; j < cnt; ++j) {
      int i0 = __shfl(vidx, j, 64);
      unsigned u0 = *reinterpret_cast<const unsigned*>(hb + (size_t)i0 * D_HID + lane * 2);
      sx0 += bf_lo(u0); sy0 += bf_hi(u0);
    }
  }
  float2 o; o.x = sx0 + sx1; o.y = sy0 + sy1;
  *reinterpret_cast<float2*>(agg + (size_t)node * D_HID + lane * 2) = o;
}

// hb_out = bf16(agg @ W + b) ; W in LDS; 32 nodes/chunk; thread = 4 nodes x 4 cols,
// k register-blocked by 4 (8 ds_read_b128 per 64 FMA)
__global__ __launch_bounds__(256) void gin_gemm_kernel(const float* __restrict__ agg,
                                                       const float* __restrict__ W,
                                                       const float* __restrict__ b,
                                                       unsigned short* __restrict__ hbout,
                                                       int numChunks) {
  __shared__ float Wlds[D_HID * D_HID];  // 64 KB
  __shared__ float arow[32 * D_HID];     // 16 KB
  for (int i = threadIdx.x; i < D_HID * D_HID; i += 256) Wlds[i] = W[i];
  const int cg = threadIdx.x >> 5;          // 0..7
  const int d0 = (threadIdx.x & 31) << 2;   // column group
  const float4 bias = *reinterpret_cast<const float4*>(b + d0);
  for (int chunk = blockIdx.x; chunk < numChunks; chunk += gridDim.x) {
    const int nodeBase = chunk * 32;
    __syncthreads();  // protects Wlds (first iter) and arow reuse (later iters)
    for (int i = threadIdx.x; i < 32 * (D_HID / 4); i += 256) {
      const int nn = nodeBase + (i >> 5);
      float4 v = {0.f, 0.f, 0.f, 0.f};
      if (nn < N_NODES)
        v = *reinterpret_cast<const float4*>(agg + (size_t)nn * D_HID + (size_t)(i & 31) * 4);
      reinterpret_cast<float4*>(arow)[i] = v;
    }
    __syncthreads();
    float4 a0 = {0,0,0,0}, a1 = {0,0,0,0}, a2 = {0,0,0,0}, a3 = {0,0,0,0};
    #pragma unroll 2
    for (int k4 = 0; k4 < 32; ++k4) {
      const int k = k4 * 4;
      const float4 w0 = *reinterpret_cast<const float4*>(&Wlds[(k + 0) * D_HID + d0]);
      const float4 w1 = *reinterpret_cast<const float4*>(&Wlds[(k + 1) * D_HID + d0]);
      const float4 w2 = *reinterpret_cast<const float4*>(&Wlds[(k + 2) * D_HID + d0]);
      const float4 w3 = *reinterpret_cast<const float4*>(&Wlds[(k + 3) * D_HID + d0]);
      const float4 va = *reinterpret_cast<const float4*>(&arow[(cg +  0) * D_HID + k]);
      const float4 vb = *reinterpret_cast<const float4*>(&arow[(cg +  8) * D_HID + k]);
      const float4 vc = *reinterpret_cast<const float4*>(&arow[(cg + 16) * D_HID + k]);
      const float4 vd = *reinterpret_cast<const float4*>(&arow[(cg + 24) * D_HID + k]);
      a0.x += va.x*w0.x + va.y*w1.x + va.z*w2.x + va.w*w3.x;
      a0.y += va.x*w0.y + va.y*w1.y + va.z*w2.y + va.w*w3.y;
      a0.z += va.x*w0.z + va.y*w1.z + va.z*w2.z + va.w*w3.z;
      a0.w += va.x*w0.w + va.y*w1.w + va.z*w2.w + va.w*w3.w;
      a1.x += vb.x*w0.x + vb.y*w1.x + vb.z*w2.x + vb.w*w3.x;
      a1.y += vb.x*w0.y + vb.y*w1.y + vb.z*w2.y + vb.w*w3.y;
      a1.z += vb.x*w0.z + vb.y*w1.z + vb.z*w2.z + vb.w*w3.z;
      a1.w += vb.x*w0.w + vb.y*w1.w + vb.z*w2.w + vb.w*w3.w;
      a2.x += vc.x*w0.x + vc.y*w1.x + vc.z*w2.x + vc.w*w3.x;
      a2.y += vc.x*w0.y + vc.y*w1.y + vc.z*w2.y + vc.w*w3.y;
      a2.z += vc.x*w0.z + vc.y*w1.z + vc.z*w2.z + vc.w*w3.z;
      a2.w += vc.x*w0.w + vc.y*w1.w + vc.z*w2.w + vc.w*w3.w;
      a3.x += vd.x*w0.x + vd.y*w1.x + vd.z*w2.x + vd.w*w3.x;
      a3.y += vd.x*w0.y + vd.y*w1.y + vd.z*w2.y + vd.w*w3.y;
      a3.z += vd.x*w0.z + vd.y*w1.z + vd.z*w2.z + vd.w*w3.z;
      a3.w += vd.x*w0.w + vd.y*w1.w + vd.z*w2.w + vd.w*w3.w;
    }
    #pragma unroll
    for (int r = 0; r < 4; ++r) {
      const int node = nodeBase + cg + r * 8;
      if (node < N_NODES) {
        float4 acc = (r == 0) ? a0 : (r == 1) ? a1 : (r == 2) ? a2 : a3;
        uint2 pk;
        pk.x = pack_bf16(acc.x + bias.x, acc.y + bias.y);
        pk.y = pack_bf16(acc.z + bias.z, acc.w + bias.w);
        *reinterpret_cast<uint2*>(hbout + (size_t)node * D_HID + d0) = pk;
      }
    }
  }
}

// out[g, layer*128 + 4c..4c+3] = sum over nodes in graph g of h[n, 4c..4c+3]
// 32 threads per graph (32 x 2 x bf16x2 = 128 cols), 8 graphs per 256-thread block
__global__ __launch_bounds__(256) void pool_kernel(const unsigned short* __restrict__ hb,
                                                   const int* __restrict__ goff,
                                                   float* __restrict__ out, int layer) {
  const int g = blockIdx.x * 8 + (threadIdx.x >> 5);
  const int t = threadIdx.x & 31;   // column group: cols 4t..4t+3
  if (g >= N_GRAPHS) return;
  const int n0 = goff[g], n1 = goff[g + 1];
  float4 s = {0.f, 0.f, 0.f, 0.f};
  int n = n0;
  for (; n + 1 < n1; n += 2) {
    uint2 v = *reinterpret_cast<const uint2*>(hb + (size_t)n * D_HID + t * 4);
    uint2 w = *reinterpret_cast<const uint2*>(hb + (size_t)(n + 1) * D_HID + t * 4);
    s.x += bf_lo(v.x) + bf_lo(w.x); s.y += bf_hi(v.x) + bf_hi(w.x);
    s.z += bf_lo(v.y) + bf_lo(w.y); s.w += bf_hi(v.y) + bf_hi(w.y);
  }
  if (n < n1) {
    uint2 v = *reinterpret_cast<const uint2*>(hb + (size_t)n * D_HID + t * 4);
    s.x += bf_lo(v.x); s.y += bf_hi(v.x); s.z += bf_lo(v.y); s.w += bf_hi(v.y);
  }
  *reinterpret_cast<float4*>(out + (size_t)g * ((N_LAYERS + 1) * D_HID) + layer * D_HID + t * 4) = s;
}

// ---------------- launch ----------------

extern "C" void kernel_launch(void* const* d_in, const int* in_sizes, int n_in,
                              void* d_out, int out_size, void* d_ws, size_t ws_size,
                              hipStream_t stream) {
  const float* x       = (const float*)d_in[0];
  const int*   edges   = (const int*)d_in[1];
  const int*   src     = edges;
  const int*   dst     = edges + N_EDGES;
  const int*   batch   = (const int*)d_in[2];
  const float* W_embed = (const float*)d_in[3];
  const float* Ws      = (const float*)d_in[4];
  const float* bs      = (const float*)d_in[5];
  float* out = (float*)d_out;

  unsigned short* hb0 = (unsigned short*)d_ws;               // 50000*128 bf16
  unsigned short* hb1 = hb0 + (size_t)N_NODES * D_HID;       // 50000*128 bf16
  float* agg = (float*)(hb1 + (size_t)N_NODES * D_HID);      // 50000*128 f32
  int*   off    = (int*)(agg + (size_t)N_NODES * D_HID);     // N+1
  int*   cursor = off + (N_NODES + 1);                       // N
  int*   csr    = cursor + N_NODES;                          // E
  int*   goff   = csr + N_EDGES;                             // G+1

  // CSR build (edge list is layer-invariant)
  zero_int_kernel<<<(N_NODES + 255) / 256, 256, 0, stream>>>(cursor, N_NODES);
  degree_kernel<<<(N_EDGES + 255) / 256, 256, 0, stream>>>(dst, cursor);
  scan_kernel<<<1, 1024, 0, stream>>>(cursor, off, N_NODES);
  copy_int_kernel<<<(N_NODES + 255) / 256, 256, 0, stream>>>(off, cursor, N_NODES);
  fill_csr_kernel<<<(N_EDGES + 255) / 256, 256, 0, stream>>>(src, dst, cursor, csr);
  graph_off_kernel<<<(N_GRAPHS + 1 + 255) / 256, 256, 0, stream>>>(batch, goff);

  // embedding + pool of feature 0
  embed_kernel<<<(N_NODES + 63) / 64, 256, 0, stream>>>(x, W_embed, hb0);
  pool_kernel<<<N_GRAPHS / 8, 256, 0, stream>>>(hb0, goff, out, 0);

  const int numChunks = (N_NODES + 31) / 32;
  unsigned short* hc = hb0;
  unsigned short* hn = hb1;
  for (int l = 0; l < N_LAYERS; ++l) {
    gather_kernel<<<(N_NODES * 64 + 255) / 256, 256, 0, stream>>>(hc, off, csr, agg);
    gin_gemm_kernel<<<512, 256, 0, stream>>>(agg,
                                             Ws + (size_t)l * D_HID * D_HID,
                                             bs + (size_t)l * D_HID, hn, numChunks);
    pool_kernel<<<N_GRAPHS / 8, 256, 0, stream>>>(hn, goff, out, l + 1);
    unsigned short* t = hc; hc = hn; hn = t;
  }
}

// Round 5
// 472.147 us; speedup vs baseline: 1.7904x; 1.2267x over previous
//
#include <hip/hip_runtime.h>

#define N_NODES 50000
#define N_EDGES 800000
#define N_GRAPHS 1024
#define N_LAYERS 5
#define D_IN 32
#define D_HID 128

typedef __attribute__((ext_vector_type(8))) short bf16x8;
typedef __attribute__((ext_vector_type(4))) float f32x4;

// ---------------- bf16 helpers ----------------

__device__ __forceinline__ float bf_lo(unsigned u) { return __uint_as_float(u << 16); }
__device__ __forceinline__ float bf_hi(unsigned u) { return __uint_as_float(u & 0xffff0000u); }
__device__ __forceinline__ unsigned bf16_rn(float f) {
  unsigned u = __float_as_uint(f);
  return (u + 0x7fffu + ((u >> 16) & 1u)) >> 16;  // round-to-nearest-even
}
__device__ __forceinline__ unsigned pack_bf16(float a, float b) {
  return bf16_rn(a) | (bf16_rn(b) << 16);
}

// ---------------- CSR build ----------------

__global__ void zero_int_kernel(int* __restrict__ p, int n) {
  int i = blockIdx.x * blockDim.x + threadIdx.x;
  if (i < n) p[i] = 0;
}

__global__ void degree_kernel(const int* __restrict__ dst, int* __restrict__ deg) {
  int e = blockIdx.x * blockDim.x + threadIdx.x;
  if (e < N_EDGES) atomicAdd(&deg[dst[e]], 1);
}

// single-block exclusive scan: off[0..n-1] = exclusive prefix, off[n] = total.
// Also writes the same prefix into cursor[] (used by fill_csr).
__global__ __launch_bounds__(1024) void scan_kernel(const int* __restrict__ deg,
                                                    int* __restrict__ off,
                                                    int* __restrict__ cursor, int n) {
  __shared__ int wsum[16];
  __shared__ int carry;
  const int tid = threadIdx.x;
  const int lane = tid & 63;
  const int w = tid >> 6;
  if (tid == 0) carry = 0;
  __syncthreads();
  for (int base = 0; base < n; base += 1024) {
    int i = base + tid;
    int v = (i < n) ? deg[i] : 0;
    int x = v;  // inclusive wave scan
    #pragma unroll
    for (int s = 1; s < 64; s <<= 1) {
      int t = __shfl_up(x, s, 64);
      if (lane >= s) x += t;
    }
    if (lane == 63) wsum[w] = x;
    __syncthreads();
    if (tid == 0) {
      int acc = 0;
      #pragma unroll
      for (int j = 0; j < 16; ++j) { int t = wsum[j]; wsum[j] = acc; acc += t; }
    }
    __syncthreads();
    int exc = carry + wsum[w] + (x - v);
    if (i < n) { off[i] = exc; cursor[i] = exc; }
    __syncthreads();                        // all threads have read carry
    if (tid == 1023) carry += wsum[15] + x;
    __syncthreads();
  }
  if (tid == 0) off[n] = carry;
}

__global__ void fill_csr_kernel(const int* __restrict__ src, const int* __restrict__ dst,
                                int* __restrict__ cursor, int* __restrict__ csr_src) {
  int e = blockIdx.x * blockDim.x + threadIdx.x;
  if (e < N_EDGES) {
    int d = dst[e];
    int pos = atomicAdd(&cursor[d], 1);
    csr_src[pos] = src[e];
  }
}

// goff[g] = lower_bound(batch, g); batch is sorted
__global__ void graph_off_kernel(const int* __restrict__ batch, int* __restrict__ goff) {
  int g = blockIdx.x * blockDim.x + threadIdx.x;
  if (g <= N_GRAPHS) {
    int lo = 0, hi = N_NODES;
    while (lo < hi) { int mid = (lo + hi) >> 1; if (batch[mid] < g) lo = mid + 1; else hi = mid; }
    goff[g] = lo;
  }
}

// ---------------- W packing for MFMA (once per launch) ----------------
// B-frag layout for v_mfma_f32_16x16x32_bf16: lane l, elem i holds
// B[k = kt*32 + (l>>4)*8 + i][col = nt*16 + (l&15)].
// Tile id t = nt*4 + kt; tile = 512 bf16 (1 KB), lane-major.
// hi/lo split: W ≈ hi + lo (bf16 each) so weight rounding ~f32-exact.
__global__ void pack_w_kernel(const float* __restrict__ Ws,
                              unsigned short* __restrict__ wb_hi,
                              unsigned short* __restrict__ wb_lo) {
  int idx = blockIdx.x * blockDim.x + threadIdx.x;
  if (idx >= N_LAYERS * 16384) return;
  int layer = idx >> 14;
  int r = idx & 16383;
  int t = r >> 9;            // 0..31
  int lane = (r >> 3) & 63;
  int i = r & 7;
  int nt = t >> 2, kt = t & 3;
  int k = kt * 32 + (lane >> 4) * 8 + i;
  int c = nt * 16 + (lane & 15);
  float f = Ws[(size_t)layer * 16384 + k * D_HID + c];
  unsigned short h = (unsigned short)bf16_rn(f);
  float hf = __uint_as_float(((unsigned)h) << 16);
  unsigned short l = (unsigned short)bf16_rn(f - hf);
  wb_hi[idx] = h;
  wb_lo[idx] = l;
}

// ---------------- compute ----------------

// hb = bf16(x @ W_embed) ; block = 64 nodes; thread computes 2 adjacent cols
__global__ __launch_bounds__(256) void embed_kernel(const float* __restrict__ x,
                                                    const float* __restrict__ W,
                                                    unsigned short* __restrict__ hb) {
  __shared__ float Wl[D_IN * D_HID];  // 16 KB
  __shared__ float xl[64 * D_IN];     // 8 KB
  for (int i = threadIdx.x; i < D_IN * D_HID; i += 256) Wl[i] = W[i];
  const int base = blockIdx.x * 64;
  const int nThis = (base + 64 <= N_NODES) ? 64 : (N_NODES - base);
  const float4* x4 = reinterpret_cast<const float4*>(x + (size_t)base * D_IN);
  for (int i = threadIdx.x; i < nThis * (D_IN / 4); i += 256)
    reinterpret_cast<float4*>(xl)[i] = x4[i];
  __syncthreads();
  const int c2 = (threadIdx.x & 63) * 2;
  const int sub = threadIdx.x >> 6;
  for (int r = sub; r < nThis; r += 4) {
    float s0 = 0.f, s1 = 0.f;
    #pragma unroll
    for (int k = 0; k < D_IN; ++k) {
      float xv = xl[r * D_IN + k];
      s0 += xv * Wl[k * D_HID + c2];
      s1 += xv * Wl[k * D_HID + c2 + 1];
    }
    *reinterpret_cast<unsigned*>(hb + (size_t)(base + r) * D_HID + c2) = pack_bf16(s0, s1);
  }
}

// aggb[n,:] = bf16( sum_{j in N(n)} h[j,:] + 2*h[n,:] )  (h read as bf16, accum f32)
__global__ __launch_bounds__(256) void gather_kernel(const unsigned short* __restrict__ hb,
                                                     const int* __restrict__ off,
                                                     const int* __restrict__ csr,
                                                     unsigned short* __restrict__ aggb) {
  const int node = (blockIdx.x * blockDim.x + threadIdx.x) >> 6;
  const int lane = threadIdx.x & 63;
  if (node >= N_NODES) return;
  const unsigned su = *reinterpret_cast<const unsigned*>(hb + (size_t)node * D_HID + lane * 2);
  float sx0 = 2.f * bf_lo(su), sy0 = 2.f * bf_hi(su), sx1 = 0.f, sy1 = 0.f;
  const int e0 = off[node], e1 = off[node + 1];
  for (int base = e0; base < e1; base += 64) {
    int cnt = e1 - base; if (cnt > 64) cnt = 64;
    int vidx = (base + lane < e1) ? csr[base + lane] : 0;
    int j = 0;
    for (; j + 4 <= cnt; j += 4) {
      int i0 = __shfl(vidx, j, 64);
      int i1 = __shfl(vidx, j + 1, 64);
      int i2 = __shfl(vidx, j + 2, 64);
      int i3 = __shfl(vidx, j + 3, 64);
      unsigned u0 = *reinterpret_cast<const unsigned*>(hb + (size_t)i0 * D_HID + lane * 2);
      unsigned u1 = *reinterpret_cast<const unsigned*>(hb + (size_t)i1 * D_HID + lane * 2);
      unsigned u2 = *reinterpret_cast<const unsigned*>(hb + (size_t)i2 * D_HID + lane * 2);
      unsigned u3 = *reinterpret_cast<const unsigned*>(hb + (size_t)i3 * D_HID + lane * 2);
      sx0 += bf_lo(u0) + bf_lo(u1); sy0 += bf_hi(u0) + bf_hi(u1);
      sx1 += bf_lo(u2) + bf_lo(u3); sy1 += bf_hi(u2) + bf_hi(u3);
    }
    for (; j < cnt; ++j) {
      int i0 = __shfl(vidx, j, 64);
      unsigned u0 = *reinterpret_cast<const unsigned*>(hb + (size_t)i0 * D_HID + lane * 2);
      sx0 += bf_lo(u0); sy0 += bf_hi(u0);
    }
  }
  *reinterpret_cast<unsigned*>(aggb + (size_t)node * D_HID + lane * 2) =
      pack_bf16(sx0 + sx1, sy0 + sy1);
}

// hb_out = bf16(aggb @ W + b) via MFMA. Block = 4 waves x 16 nodes = 64 nodes.
// A-frag: lane l holds agg[base_m + (l&15)][kt*32 + (l>>4)*8 .. +8) (one 16B load).
// B-frag: packed tiles from pack_w_kernel (1KB coalesced load per frag).
// D: col = lane&15, row = (lane>>4)*4 + reg  (m89/m91-verified layout).
// N_NODES % 16 == 0, so active waves have all rows valid.
__global__ __launch_bounds__(256) void gin_gemm_mfma(const unsigned short* __restrict__ aggb,
                                                     const unsigned short* __restrict__ wb_hi,
                                                     const unsigned short* __restrict__ wb_lo,
                                                     const float* __restrict__ b,
                                                     unsigned short* __restrict__ hbout) {
  const int wave = threadIdx.x >> 6;
  const int lane = threadIdx.x & 63;
  const int base_m = blockIdx.x * 64 + wave * 16;
  if (base_m >= N_NODES) return;
  const int lg = lane >> 4;    // 0..3
  const int l15 = lane & 15;
  bf16x8 a[4];
  const unsigned short* abase = aggb + (size_t)(base_m + l15) * D_HID + lg * 8;
  #pragma unroll
  for (int kt = 0; kt < 4; ++kt)
    a[kt] = *reinterpret_cast<const bf16x8*>(abase + kt * 32);
  #pragma unroll
  for (int nt = 0; nt < 8; ++nt) {
    f32x4 acc = {0.f, 0.f, 0.f, 0.f};
    #pragma unroll
    for (int kt = 0; kt < 4; ++kt) {
      const int toff = (nt * 4 + kt) * 512 + lane * 8;
      bf16x8 bh = *reinterpret_cast<const bf16x8*>(wb_hi + toff);
      bf16x8 bl = *reinterpret_cast<const bf16x8*>(wb_lo + toff);
      acc = __builtin_amdgcn_mfma_f32_16x16x32_bf16(a[kt], bh, acc, 0, 0, 0);
      acc = __builtin_amdgcn_mfma_f32_16x16x32_bf16(a[kt], bl, acc, 0, 0, 0);
    }
    const int col = nt * 16 + l15;
    const float bcol = b[col];
    #pragma unroll
    for (int i = 0; i < 4; ++i) {
      const int node = base_m + lg * 4 + i;
      hbout[(size_t)node * D_HID + col] = (unsigned short)bf16_rn(acc[i] + bcol);
    }
  }
}

// out[g, layer*128 + 4c..4c+3] = sum over nodes in graph g
// 32 threads per graph, 8 graphs per 256-thread block
__global__ __launch_bounds__(256) void pool_kernel(const unsigned short* __restrict__ hb,
                                                   const int* __restrict__ goff,
                                                   float* __restrict__ out, int layer) {
  const int g = blockIdx.x * 8 + (threadIdx.x >> 5);
  const int t = threadIdx.x & 31;
  if (g >= N_GRAPHS) return;
  const int n0 = goff[g], n1 = goff[g + 1];
  float4 s = {0.f, 0.f, 0.f, 0.f};
  int n = n0;
  for (; n + 1 < n1; n += 2) {
    uint2 v = *reinterpret_cast<const uint2*>(hb + (size_t)n * D_HID + t * 4);
    uint2 w = *reinterpret_cast<const uint2*>(hb + (size_t)(n + 1) * D_HID + t * 4);
    s.x += bf_lo(v.x) + bf_lo(w.x); s.y += bf_hi(v.x) + bf_hi(w.x);
    s.z += bf_lo(v.y) + bf_lo(w.y); s.w += bf_hi(v.y) + bf_hi(w.y);
  }
  if (n < n1) {
    uint2 v = *reinterpret_cast<const uint2*>(hb + (size_t)n * D_HID + t * 4);
    s.x += bf_lo(v.x); s.y += bf_hi(v.x); s.z += bf_lo(v.y); s.w += bf_hi(v.y);
  }
  *reinterpret_cast<float4*>(out + (size_t)g * ((N_LAYERS + 1) * D_HID) + layer * D_HID + t * 4) = s;
}

// ---------------- launch ----------------

extern "C" void kernel_launch(void* const* d_in, const int* in_sizes, int n_in,
                              void* d_out, int out_size, void* d_ws, size_t ws_size,
                              hipStream_t stream) {
  const float* x       = (const float*)d_in[0];
  const int*   edges   = (const int*)d_in[1];
  const int*   src     = edges;
  const int*   dst     = edges + N_EDGES;
  const int*   batch   = (const int*)d_in[2];
  const float* W_embed = (const float*)d_in[3];
  const float* Ws      = (const float*)d_in[4];
  const float* bs      = (const float*)d_in[5];
  float* out = (float*)d_out;

  unsigned short* hb0  = (unsigned short*)d_ws;               // 50000*128 bf16
  unsigned short* hb1  = hb0 + (size_t)N_NODES * D_HID;       // 50000*128 bf16
  unsigned short* aggb = hb1 + (size_t)N_NODES * D_HID;       // 50000*128 bf16
  unsigned short* wb_hi = aggb + (size_t)N_NODES * D_HID;     // 5*16384 bf16
  unsigned short* wb_lo = wb_hi + (size_t)N_LAYERS * 16384;   // 5*16384 bf16
  int*   off    = (int*)(wb_lo + (size_t)N_LAYERS * 16384);   // N+1
  int*   cursor = off + (N_NODES + 1);                        // N
  int*   csr    = cursor + N_NODES;                           // E
  int*   goff   = csr + N_EDGES;                              // G+1

  // CSR build (edge list is layer-invariant)
  zero_int_kernel<<<(N_NODES + 255) / 256, 256, 0, stream>>>(cursor, N_NODES);
  degree_kernel<<<(N_EDGES + 255) / 256, 256, 0, stream>>>(dst, cursor);
  scan_kernel<<<1, 1024, 0, stream>>>(cursor, off, cursor, N_NODES);
  fill_csr_kernel<<<(N_EDGES + 255) / 256, 256, 0, stream>>>(src, dst, cursor, csr);
  graph_off_kernel<<<(N_GRAPHS + 1 + 255) / 256, 256, 0, stream>>>(batch, goff);

  // W packing for MFMA
  pack_w_kernel<<<(N_LAYERS * 16384 + 255) / 256, 256, 0, stream>>>(Ws, wb_hi, wb_lo);

  // embedding + pool of feature 0
  embed_kernel<<<(N_NODES + 63) / 64, 256, 0, stream>>>(x, W_embed, hb0);
  pool_kernel<<<N_GRAPHS / 8, 256, 0, stream>>>(hb0, goff, out, 0);

  unsigned short* hc = hb0;
  unsigned short* hn = hb1;
  for (int l = 0; l < N_LAYERS; ++l) {
    gather_kernel<<<(N_NODES * 64 + 255) / 256, 256, 0, stream>>>(hc, off, csr, aggb);
    gin_gemm_mfma<<<(N_NODES + 63) / 64, 256, 0, stream>>>(aggb,
                                                           wb_hi + (size_t)l * 16384,
                                                           wb_lo + (size_t)l * 16384,
                                                           bs + (size_t)l * D_HID, hn);
    pool_kernel<<<N_GRAPHS / 8, 256, 0, stream>>>(hn, goff, out, l + 1);
    unsigned short* t = hc; hc = hn; hn = t;
  }
}

// Round 6
// 374.579 us; speedup vs baseline: 2.2568x; 1.2605x over previous
//
#include <hip/hip_runtime.h>

#define N_NODES 50000
#define N_EDGES 800000
#define N_GRAPHS 1024
#define N_LAYERS 5
#define D_IN 32
#define D_HID 128

#define NBUCK 256
#define BUCK_NODES 196   // ceil(N_NODES/NBUCK)
#define BUCK_CAP 4096    // LDS csr capacity per bucket (mean ~3125, +17 sigma)
#define CHUNK 4096
#define NCHUNKS ((N_EDGES + CHUNK - 1) / CHUNK)  // 196

typedef __attribute__((ext_vector_type(8))) short bf16x8;
typedef __attribute__((ext_vector_type(4))) float f32x4;

// ---------------- bf16 helpers ----------------

__device__ __forceinline__ float bf_lo(unsigned u) { return __uint_as_float(u << 16); }
__device__ __forceinline__ float bf_hi(unsigned u) { return __uint_as_float(u & 0xffff0000u); }
__device__ __forceinline__ unsigned bf16_rn(float f) {
  unsigned u = __float_as_uint(f);
  return (u + 0x7fffu + ((u >> 16) & 1u)) >> 16;  // round-to-nearest-even
}
__device__ __forceinline__ unsigned pack_bf16(float a, float b) {
  return bf16_rn(a) | (bf16_rn(b) << 16);
}

// ---------------- bucketed CSR build ----------------

__global__ void zero_int_kernel(int* __restrict__ p, int n) {
  int i = blockIdx.x * blockDim.x + threadIdx.x;
  if (i < n) p[i] = 0;
}

// pass 1: per-bucket edge counts
__global__ __launch_bounds__(256) void bucket_count_kernel(const int* __restrict__ dst,
                                                           int* __restrict__ bcount) {
  __shared__ int cnt[NBUCK];
  for (int i = threadIdx.x; i < NBUCK; i += 256) cnt[i] = 0;
  __syncthreads();
  const int cb = blockIdx.x * CHUNK;
  const int end = (cb + CHUNK < N_EDGES) ? cb + CHUNK : N_EDGES;
  for (int e = cb + threadIdx.x; e < end; e += 256)
    atomicAdd(&cnt[dst[e] / BUCK_NODES], 1);
  __syncthreads();
  for (int i = threadIdx.x; i < NBUCK; i += 256)
    if (cnt[i]) atomicAdd(&bcount[i], cnt[i]);
}

// pass 1b: scan 256 bucket counts -> bbase[0..256]; gcur = exclusive base
__global__ __launch_bounds__(256) void bucket_scan_kernel(const int* __restrict__ bcount,
                                                          int* __restrict__ bbase,
                                                          int* __restrict__ gcur) {
  __shared__ int s[NBUCK];
  const int t = threadIdx.x;
  const int v0 = bcount[t];
  s[t] = v0;
  __syncthreads();
  #pragma unroll
  for (int d = 1; d < NBUCK; d <<= 1) {
    int v = (t >= d) ? s[t - d] : 0;
    __syncthreads();
    s[t] += v;
    __syncthreads();
  }
  bbase[t + 1] = s[t];
  if (t == 0) bbase[0] = 0;
  gcur[t] = s[t] - v0;  // exclusive prefix
}

// pass 2: partition edges into per-bucket-contiguous aux regions (packed dst<<32|src)
__global__ __launch_bounds__(256) void bucket_scatter_kernel(const int* __restrict__ src,
                                                             const int* __restrict__ dst,
                                                             int* __restrict__ gcur,
                                                             unsigned long long* __restrict__ aux) {
  __shared__ int cnt[NBUCK];
  __shared__ int base_[NBUCK];
  __shared__ int cur[NBUCK];
  for (int i = threadIdx.x; i < NBUCK; i += 256) cnt[i] = 0;
  __syncthreads();
  const int cb = blockIdx.x * CHUNK;
  const int end = (cb + CHUNK < N_EDGES) ? cb + CHUNK : N_EDGES;
  for (int e = cb + threadIdx.x; e < end; e += 256)
    atomicAdd(&cnt[dst[e] / BUCK_NODES], 1);
  __syncthreads();
  for (int i = threadIdx.x; i < NBUCK; i += 256) {
    base_[i] = cnt[i] ? atomicAdd(&gcur[i], cnt[i]) : 0;
    cur[i] = 0;
  }
  __syncthreads();
  for (int e = cb + threadIdx.x; e < end; e += 256) {
    const int d = dst[e];
    const int b = d / BUCK_NODES;
    const int p = base_[b] + atomicAdd(&cur[b], 1);
    aux[p] = ((unsigned long long)(unsigned)d << 32) | (unsigned)src[e];
  }
}

// pass 3: per-bucket fine CSR in LDS, streamed out coalesced; writes off[]
__global__ __launch_bounds__(256) void bucket_csr_kernel(const unsigned long long* __restrict__ aux,
                                                         const int* __restrict__ bbase,
                                                         int* __restrict__ off,
                                                         int* __restrict__ csr) {
  __shared__ int sdeg[NBUCK];
  __shared__ int sscan[NBUCK];
  __shared__ int scur[NBUCK];
  __shared__ int lcsr[BUCK_CAP];
  const int b = blockIdx.x, t = threadIdx.x;
  const int e0 = bbase[b], e1 = bbase[b + 1];
  const int n0 = b * BUCK_NODES;
  const int nN = (N_NODES - n0 < BUCK_NODES) ? (N_NODES - n0) : BUCK_NODES;
  sdeg[t] = 0;
  __syncthreads();
  for (int i = e0 + t; i < e1; i += 256)
    atomicAdd(&sdeg[(int)(aux[i] >> 32) - n0], 1);
  __syncthreads();
  // inclusive scan of sdeg -> sscan
  sscan[t] = sdeg[t];
  __syncthreads();
  #pragma unroll
  for (int d = 1; d < NBUCK; d <<= 1) {
    int v = (t >= d) ? sscan[t - d] : 0;
    __syncthreads();
    sscan[t] += v;
    __syncthreads();
  }
  // exclusive
  const int exc_t = sscan[t] - sdeg[t];
  __syncthreads();
  sscan[t] = exc_t;
  scur[t] = 0;
  if (t < nN) off[n0 + t] = e0 + exc_t;
  if (b == NBUCK - 1 && t == 0) off[N_NODES] = e1;
  __syncthreads();
  for (int i = e0 + t; i < e1; i += 256) {
    const unsigned long long v = aux[i];
    const int d = (int)(v >> 32) - n0;
    const int pos = sscan[d] + atomicAdd(&scur[d], 1);
    const int s = (int)(unsigned)(v & 0xffffffffu);
    if (pos < BUCK_CAP) lcsr[pos] = s;
    else csr[e0 + pos] = s;  // overflow guard (statistically never)
  }
  __syncthreads();
  const int cntAll = e1 - e0;
  const int lim = (cntAll < BUCK_CAP) ? cntAll : BUCK_CAP;
  for (int i = t; i < lim; i += 256) csr[e0 + i] = lcsr[i];
}

// goff[g] = lower_bound(batch, g); batch is sorted
__global__ void graph_off_kernel(const int* __restrict__ batch, int* __restrict__ goff) {
  int g = blockIdx.x * blockDim.x + threadIdx.x;
  if (g <= N_GRAPHS) {
    int lo = 0, hi = N_NODES;
    while (lo < hi) { int mid = (lo + hi) >> 1; if (batch[mid] < g) lo = mid + 1; else hi = mid; }
    goff[g] = lo;
  }
}

// ---------------- W packing for MFMA (once per launch) ----------------
// B-frag layout for v_mfma_f32_16x16x32_bf16: lane l, elem i holds
// B[k = kt*32 + (l>>4)*8 + i][col = nt*16 + (l&15)].
// hi/lo split: W ≈ hi + lo (bf16 each) so weight rounding ~f32-exact.
__global__ void pack_w_kernel(const float* __restrict__ Ws,
                              unsigned short* __restrict__ wb_hi,
                              unsigned short* __restrict__ wb_lo) {
  int idx = blockIdx.x * blockDim.x + threadIdx.x;
  if (idx >= N_LAYERS * 16384) return;
  int layer = idx >> 14;
  int r = idx & 16383;
  int t = r >> 9;            // 0..31
  int lane = (r >> 3) & 63;
  int i = r & 7;
  int nt = t >> 2, kt = t & 3;
  int k = kt * 32 + (lane >> 4) * 8 + i;
  int c = nt * 16 + (lane & 15);
  float f = Ws[(size_t)layer * 16384 + k * D_HID + c];
  unsigned short h = (unsigned short)bf16_rn(f);
  float hf = __uint_as_float(((unsigned)h) << 16);
  unsigned short l = (unsigned short)bf16_rn(f - hf);
  wb_hi[idx] = h;
  wb_lo[idx] = l;
}

// ---------------- compute ----------------

// hb = bf16(x @ W_embed) ; block = 64 nodes; thread computes 2 adjacent cols
__global__ __launch_bounds__(256) void embed_kernel(const float* __restrict__ x,
                                                    const float* __restrict__ W,
                                                    unsigned short* __restrict__ hb) {
  __shared__ float Wl[D_IN * D_HID];  // 16 KB
  __shared__ float xl[64 * D_IN];     // 8 KB
  for (int i = threadIdx.x; i < D_IN * D_HID; i += 256) Wl[i] = W[i];
  const int base = blockIdx.x * 64;
  const int nThis = (base + 64 <= N_NODES) ? 64 : (N_NODES - base);
  const float4* x4 = reinterpret_cast<const float4*>(x + (size_t)base * D_IN);
  for (int i = threadIdx.x; i < nThis * (D_IN / 4); i += 256)
    reinterpret_cast<float4*>(xl)[i] = x4[i];
  __syncthreads();
  const int c2 = (threadIdx.x & 63) * 2;
  const int sub = threadIdx.x >> 6;
  for (int r = sub; r < nThis; r += 4) {
    float s0 = 0.f, s1 = 0.f;
    #pragma unroll
    for (int k = 0; k < D_IN; ++k) {
      float xv = xl[r * D_IN + k];
      s0 += xv * Wl[k * D_HID + c2];
      s1 += xv * Wl[k * D_HID + c2 + 1];
    }
    *reinterpret_cast<unsigned*>(hb + (size_t)(base + r) * D_HID + c2) = pack_bf16(s0, s1);
  }
}

// aggb[n,:] = bf16( sum_{j in N(n)} h[j,:] + 2*h[n,:] )  (h read as bf16, accum f32)
__global__ __launch_bounds__(256) void gather_kernel(const unsigned short* __restrict__ hb,
                                                     const int* __restrict__ off,
                                                     const int* __restrict__ csr,
                                                     unsigned short* __restrict__ aggb) {
  const int node = (blockIdx.x * blockDim.x + threadIdx.x) >> 6;
  const int lane = threadIdx.x & 63;
  if (node >= N_NODES) return;
  const unsigned su = *reinterpret_cast<const unsigned*>(hb + (size_t)node * D_HID + lane * 2);
  float sx0 = 2.f * bf_lo(su), sy0 = 2.f * bf_hi(su), sx1 = 0.f, sy1 = 0.f;
  const int e0 = off[node], e1 = off[node + 1];
  for (int base = e0; base < e1; base += 64) {
    int cnt = e1 - base; if (cnt > 64) cnt = 64;
    int vidx = (base + lane < e1) ? csr[base + lane] : 0;
    int j = 0;
    for (; j + 4 <= cnt; j += 4) {
      int i0 = __shfl(vidx, j, 64);
      int i1 = __shfl(vidx, j + 1, 64);
      int i2 = __shfl(vidx, j + 2, 64);
      int i3 = __shfl(vidx, j + 3, 64);
      unsigned u0 = *reinterpret_cast<const unsigned*>(hb + (size_t)i0 * D_HID + lane * 2);
      unsigned u1 = *reinterpret_cast<const unsigned*>(hb + (size_t)i1 * D_HID + lane * 2);
      unsigned u2 = *reinterpret_cast<const unsigned*>(hb + (size_t)i2 * D_HID + lane * 2);
      unsigned u3 = *reinterpret_cast<const unsigned*>(hb + (size_t)i3 * D_HID + lane * 2);
      sx0 += bf_lo(u0) + bf_lo(u1); sy0 += bf_hi(u0) + bf_hi(u1);
      sx1 += bf_lo(u2) + bf_lo(u3); sy1 += bf_hi(u2) + bf_hi(u3);
    }
    for (; j < cnt; ++j) {
      int i0 = __shfl(vidx, j, 64);
      unsigned u0 = *reinterpret_cast<const unsigned*>(hb + (size_t)i0 * D_HID + lane * 2);
      sx0 += bf_lo(u0); sy0 += bf_hi(u0);
    }
  }
  *reinterpret_cast<unsigned*>(aggb + (size_t)node * D_HID + lane * 2) =
      pack_bf16(sx0 + sx1, sy0 + sy1);
}

// hb_out = bf16(aggb @ W + b) via MFMA. Block = 4 waves x 16 nodes = 64 nodes.
__global__ __launch_bounds__(256) void gin_gemm_mfma(const unsigned short* __restrict__ aggb,
                                                     const unsigned short* __restrict__ wb_hi,
                                                     const unsigned short* __restrict__ wb_lo,
                                                     const float* __restrict__ b,
                                                     unsigned short* __restrict__ hbout) {
  const int wave = threadIdx.x >> 6;
  const int lane = threadIdx.x & 63;
  const int base_m = blockIdx.x * 64 + wave * 16;
  if (base_m >= N_NODES) return;
  const int lg = lane >> 4;    // 0..3
  const int l15 = lane & 15;
  bf16x8 a[4];
  const unsigned short* abase = aggb + (size_t)(base_m + l15) * D_HID + lg * 8;
  #pragma unroll
  for (int kt = 0; kt < 4; ++kt)
    a[kt] = *reinterpret_cast<const bf16x8*>(abase + kt * 32);
  #pragma unroll
  for (int nt = 0; nt < 8; ++nt) {
    f32x4 acc = {0.f, 0.f, 0.f, 0.f};
    #pragma unroll
    for (int kt = 0; kt < 4; ++kt) {
      const int toff = (nt * 4 + kt) * 512 + lane * 8;
      bf16x8 bh = *reinterpret_cast<const bf16x8*>(wb_hi + toff);
      bf16x8 bl = *reinterpret_cast<const bf16x8*>(wb_lo + toff);
      acc = __builtin_amdgcn_mfma_f32_16x16x32_bf16(a[kt], bh, acc, 0, 0, 0);
      acc = __builtin_amdgcn_mfma_f32_16x16x32_bf16(a[kt], bl, acc, 0, 0, 0);
    }
    const int col = nt * 16 + l15;
    const float bcol = b[col];
    #pragma unroll
    for (int i = 0; i < 4; ++i) {
      const int node = base_m + lg * 4 + i;
      hbout[(size_t)node * D_HID + col] = (unsigned short)bf16_rn(acc[i] + bcol);
    }
  }
}

// out[g, layer*128 + 4c..4c+3] = sum over nodes in graph g
__global__ __launch_bounds__(256) void pool_kernel(const unsigned short* __restrict__ hb,
                                                   const int* __restrict__ goff,
                                                   float* __restrict__ out, int layer) {
  const int g = blockIdx.x * 8 + (threadIdx.x >> 5);
  const int t = threadIdx.x & 31;
  if (g >= N_GRAPHS) return;
  const int n0 = goff[g], n1 = goff[g + 1];
  float4 s = {0.f, 0.f, 0.f, 0.f};
  int n = n0;
  for (; n + 1 < n1; n += 2) {
    uint2 v = *reinterpret_cast<const uint2*>(hb + (size_t)n * D_HID + t * 4);
    uint2 w = *reinterpret_cast<const uint2*>(hb + (size_t)(n + 1) * D_HID + t * 4);
    s.x += bf_lo(v.x) + bf_lo(w.x); s.y += bf_hi(v.x) + bf_hi(w.x);
    s.z += bf_lo(v.y) + bf_lo(w.y); s.w += bf_hi(v.y) + bf_hi(w.y);
  }
  if (n < n1) {
    uint2 v = *reinterpret_cast<const uint2*>(hb + (size_t)n * D_HID + t * 4);
    s.x += bf_lo(v.x); s.y += bf_hi(v.x); s.z += bf_lo(v.y); s.w += bf_hi(v.y);
  }
  *reinterpret_cast<float4*>(out + (size_t)g * ((N_LAYERS + 1) * D_HID) + layer * D_HID + t * 4) = s;
}

// ---------------- launch ----------------

extern "C" void kernel_launch(void* const* d_in, const int* in_sizes, int n_in,
                              void* d_out, int out_size, void* d_ws, size_t ws_size,
                              hipStream_t stream) {
  const float* x       = (const float*)d_in[0];
  const int*   edges   = (const int*)d_in[1];
  const int*   src     = edges;
  const int*   dst     = edges + N_EDGES;
  const int*   batch   = (const int*)d_in[2];
  const float* W_embed = (const float*)d_in[3];
  const float* Ws      = (const float*)d_in[4];
  const float* bs      = (const float*)d_in[5];
  float* out = (float*)d_out;

  unsigned short* hb0  = (unsigned short*)d_ws;               // 50000*128 bf16
  unsigned short* hb1  = hb0 + (size_t)N_NODES * D_HID;       // 50000*128 bf16
  unsigned short* aggb = hb1 + (size_t)N_NODES * D_HID;       // 50000*128 bf16
  unsigned short* wb_hi = aggb + (size_t)N_NODES * D_HID;     // 5*16384 bf16
  unsigned short* wb_lo = wb_hi + (size_t)N_LAYERS * 16384;   // 5*16384 bf16
  unsigned long long* aux = (unsigned long long*)(wb_lo + (size_t)N_LAYERS * 16384); // E u64
  int*   off    = (int*)(aux + N_EDGES);                      // N+1
  int*   bcount = off + (N_NODES + 1);                        // 256
  int*   bbase  = bcount + NBUCK;                             // 257
  int*   gcur   = bbase + (NBUCK + 1);                        // 256
  int*   csr    = gcur + NBUCK;                               // E
  int*   goff   = csr + N_EDGES;                              // G+1

  // bucketed CSR build (edge list is layer-invariant)
  zero_int_kernel<<<1, 256, 0, stream>>>(bcount, NBUCK);
  bucket_count_kernel<<<NCHUNKS, 256, 0, stream>>>(dst, bcount);
  bucket_scan_kernel<<<1, NBUCK, 0, stream>>>(bcount, bbase, gcur);
  bucket_scatter_kernel<<<NCHUNKS, 256, 0, stream>>>(src, dst, gcur, aux);
  bucket_csr_kernel<<<NBUCK, 256, 0, stream>>>(aux, bbase, off, csr);
  graph_off_kernel<<<(N_GRAPHS + 1 + 255) / 256, 256, 0, stream>>>(batch, goff);

  // W packing for MFMA
  pack_w_kernel<<<(N_LAYERS * 16384 + 255) / 256, 256, 0, stream>>>(Ws, wb_hi, wb_lo);

  // embedding + pool of feature 0
  embed_kernel<<<(N_NODES + 63) / 64, 256, 0, stream>>>(x, W_embed, hb0);
  pool_kernel<<<N_GRAPHS / 8, 256, 0, stream>>>(hb0, goff, out, 0);

  unsigned short* hc = hb0;
  unsigned short* hn = hb1;
  for (int l = 0; l < N_LAYERS; ++l) {
    gather_kernel<<<(N_NODES * 64 + 255) / 256, 256, 0, stream>>>(hc, off, csr, aggb);
    gin_gemm_mfma<<<(N_NODES + 63) / 64, 256, 0, stream>>>(aggb,
                                                           wb_hi + (size_t)l * 16384,
                                                           wb_lo + (size_t)l * 16384,
                                                           bs + (size_t)l * D_HID, hn);
    pool_kernel<<<N_GRAPHS / 8, 256, 0, stream>>>(hn, goff, out, l + 1);
    unsigned short* t = hc; hc = hn; hn = t;
  }
}

// Round 7
// 298.375 us; speedup vs baseline: 2.8331x; 1.2554x over previous
//
#include <hip/hip_runtime.h>

#define N_NODES 50000
#define N_EDGES 800000
#define N_GRAPHS 1024
#define N_LAYERS 5
#define D_IN 32
#define D_HID 128

#define NBUCK 256
#define BUCK_NODES 196   // ceil(N_NODES/NBUCK)
#define BUCK_CAP 4096    // LDS csr capacity per bucket (mean ~3125)
#define CHUNK 4096
#define NCHUNKS ((N_EDGES + CHUNK - 1) / CHUNK)  // 196

typedef __attribute__((ext_vector_type(8))) short bf16x8;
typedef __attribute__((ext_vector_type(4))) float f32x4;

// ---------------- bf16 helpers ----------------

__device__ __forceinline__ float bf_lo(unsigned u) { return __uint_as_float(u << 16); }
__device__ __forceinline__ float bf_hi(unsigned u) { return __uint_as_float(u & 0xffff0000u); }
__device__ __forceinline__ unsigned bf16_rn(float f) {
  unsigned u = __float_as_uint(f);
  return (u + 0x7fffu + ((u >> 16) & 1u)) >> 16;  // round-to-nearest-even
}
__device__ __forceinline__ unsigned pack_bf16(float a, float b) {
  return bf16_rn(a) | (bf16_rn(b) << 16);
}

// ---------------- bucketed CSR build ----------------

__global__ void zero_int_kernel(int* __restrict__ p, int n) {
  int i = blockIdx.x * blockDim.x + threadIdx.x;
  if (i < n) p[i] = 0;
}

__global__ __launch_bounds__(256) void bucket_count_kernel(const int* __restrict__ dst,
                                                           int* __restrict__ bcount) {
  __shared__ int cnt[NBUCK];
  for (int i = threadIdx.x; i < NBUCK; i += 256) cnt[i] = 0;
  __syncthreads();
  const int cb = blockIdx.x * CHUNK;
  const int end = (cb + CHUNK < N_EDGES) ? cb + CHUNK : N_EDGES;
  for (int e = cb + threadIdx.x; e < end; e += 256)
    atomicAdd(&cnt[dst[e] / BUCK_NODES], 1);
  __syncthreads();
  for (int i = threadIdx.x; i < NBUCK; i += 256)
    if (cnt[i]) atomicAdd(&bcount[i], cnt[i]);
}

__global__ __launch_bounds__(256) void bucket_scan_kernel(const int* __restrict__ bcount,
                                                          int* __restrict__ bbase,
                                                          int* __restrict__ gcur) {
  __shared__ int s[NBUCK];
  const int t = threadIdx.x;
  const int v0 = bcount[t];
  s[t] = v0;
  __syncthreads();
  #pragma unroll
  for (int d = 1; d < NBUCK; d <<= 1) {
    int v = (t >= d) ? s[t - d] : 0;
    __syncthreads();
    s[t] += v;
    __syncthreads();
  }
  bbase[t + 1] = s[t];
  if (t == 0) bbase[0] = 0;
  gcur[t] = s[t] - v0;  // exclusive prefix
}

__global__ __launch_bounds__(256) void bucket_scatter_kernel(const int* __restrict__ src,
                                                             const int* __restrict__ dst,
                                                             int* __restrict__ gcur,
                                                             unsigned long long* __restrict__ aux) {
  __shared__ int cnt[NBUCK];
  __shared__ int base_[NBUCK];
  __shared__ int cur[NBUCK];
  for (int i = threadIdx.x; i < NBUCK; i += 256) cnt[i] = 0;
  __syncthreads();
  const int cb = blockIdx.x * CHUNK;
  const int end = (cb + CHUNK < N_EDGES) ? cb + CHUNK : N_EDGES;
  for (int e = cb + threadIdx.x; e < end; e += 256)
    atomicAdd(&cnt[dst[e] / BUCK_NODES], 1);
  __syncthreads();
  for (int i = threadIdx.x; i < NBUCK; i += 256) {
    base_[i] = cnt[i] ? atomicAdd(&gcur[i], cnt[i]) : 0;
    cur[i] = 0;
  }
  __syncthreads();
  for (int e = cb + threadIdx.x; e < end; e += 256) {
    const int d = dst[e];
    const int b = d / BUCK_NODES;
    const int p = base_[b] + atomicAdd(&cur[b], 1);
    aux[p] = ((unsigned long long)(unsigned)d << 32) | (unsigned)src[e];
  }
}

__global__ __launch_bounds__(256) void bucket_csr_kernel(const unsigned long long* __restrict__ aux,
                                                         const int* __restrict__ bbase,
                                                         int* __restrict__ off,
                                                         int* __restrict__ csr) {
  __shared__ int sdeg[NBUCK];
  __shared__ int sscan[NBUCK];
  __shared__ int scur[NBUCK];
  __shared__ int lcsr[BUCK_CAP];
  const int b = blockIdx.x, t = threadIdx.x;
  const int e0 = bbase[b], e1 = bbase[b + 1];
  const int n0 = b * BUCK_NODES;
  const int nN = (N_NODES - n0 < BUCK_NODES) ? (N_NODES - n0) : BUCK_NODES;
  sdeg[t] = 0;
  __syncthreads();
  for (int i = e0 + t; i < e1; i += 256)
    atomicAdd(&sdeg[(int)(aux[i] >> 32) - n0], 1);
  __syncthreads();
  sscan[t] = sdeg[t];
  __syncthreads();
  #pragma unroll
  for (int d = 1; d < NBUCK; d <<= 1) {
    int v = (t >= d) ? sscan[t - d] : 0;
    __syncthreads();
    sscan[t] += v;
    __syncthreads();
  }
  const int exc_t = sscan[t] - sdeg[t];
  __syncthreads();
  sscan[t] = exc_t;
  scur[t] = 0;
  if (t < nN) off[n0 + t] = e0 + exc_t;
  if (b == NBUCK - 1 && t == 0) off[N_NODES] = e1;
  __syncthreads();
  for (int i = e0 + t; i < e1; i += 256) {
    const unsigned long long v = aux[i];
    const int d = (int)(v >> 32) - n0;
    const int pos = sscan[d] + atomicAdd(&scur[d], 1);
    const int s = (int)(unsigned)(v & 0xffffffffu);
    if (pos < BUCK_CAP) lcsr[pos] = s;
    else csr[e0 + pos] = s;  // overflow guard (statistically never)
  }
  __syncthreads();
  const int cntAll = e1 - e0;
  const int lim = (cntAll < BUCK_CAP) ? cntAll : BUCK_CAP;
  for (int i = t; i < lim; i += 256) csr[e0 + i] = lcsr[i];
}

// goff[g] = lower_bound(batch, g); batch is sorted
__global__ void graph_off_kernel(const int* __restrict__ batch, int* __restrict__ goff) {
  int g = blockIdx.x * blockDim.x + threadIdx.x;
  if (g <= N_GRAPHS) {
    int lo = 0, hi = N_NODES;
    while (lo < hi) { int mid = (lo + hi) >> 1; if (batch[mid] < g) lo = mid + 1; else hi = mid; }
    goff[g] = lo;
  }
}

// ---------------- W packing for MFMA ----------------
// B-frag for v_mfma_f32_16x16x32_bf16: lane l, elem i = B[kt*32+(l>>4)*8+i][nt*16+(l&15)]
// hi/lo split keeps weights ~f32-exact.
__global__ void pack_w_kernel(const float* __restrict__ Ws,
                              unsigned short* __restrict__ wb_hi,
                              unsigned short* __restrict__ wb_lo) {
  int idx = blockIdx.x * blockDim.x + threadIdx.x;
  if (idx >= N_LAYERS * 16384) return;
  int layer = idx >> 14;
  int r = idx & 16383;
  int t = r >> 9;
  int lane = (r >> 3) & 63;
  int i = r & 7;
  int nt = t >> 2, kt = t & 3;
  int k = kt * 32 + (lane >> 4) * 8 + i;
  int c = nt * 16 + (lane & 15);
  float f = Ws[(size_t)layer * 16384 + k * D_HID + c];
  unsigned short h = (unsigned short)bf16_rn(f);
  float hf = __uint_as_float(((unsigned)h) << 16);
  unsigned short l = (unsigned short)bf16_rn(f - hf);
  wb_hi[idx] = h;
  wb_lo[idx] = l;
}

// ---------------- compute ----------------

// hb = bf16(x @ W_embed)
__global__ __launch_bounds__(256) void embed_kernel(const float* __restrict__ x,
                                                    const float* __restrict__ W,
                                                    unsigned short* __restrict__ hb) {
  __shared__ float Wl[D_IN * D_HID];
  __shared__ float xl[64 * D_IN];
  for (int i = threadIdx.x; i < D_IN * D_HID; i += 256) Wl[i] = W[i];
  const int base = blockIdx.x * 64;
  const int nThis = (base + 64 <= N_NODES) ? 64 : (N_NODES - base);
  const float4* x4 = reinterpret_cast<const float4*>(x + (size_t)base * D_IN);
  for (int i = threadIdx.x; i < nThis * (D_IN / 4); i += 256)
    reinterpret_cast<float4*>(xl)[i] = x4[i];
  __syncthreads();
  const int c2 = (threadIdx.x & 63) * 2;
  const int sub = threadIdx.x >> 6;
  for (int r = sub; r < nThis; r += 4) {
    float s0 = 0.f, s1 = 0.f;
    #pragma unroll
    for (int k = 0; k < D_IN; ++k) {
      float xv = xl[r * D_IN + k];
      s0 += xv * Wl[k * D_HID + c2];
      s1 += xv * Wl[k * D_HID + c2 + 1];
    }
    *reinterpret_cast<unsigned*>(hb + (size_t)(base + r) * D_HID + c2) = pack_bf16(s0, s1);
  }
}

// Fused GIN layer: block = 4 waves = 16 nodes.
// Phase 1 (gather): wave w gathers nodes base+4w..base+4w+3; row packed bf16 into
//   LDS A-tile with XOR swizzle: u32 index = r*64 + (lane ^ ((r&7)<<2)).
// Phase 2 (gemm): A-frag via swizzled ds_read_b128 (same k-mapping as proven R5
//   global A load); each wave computes nt = {2w, 2w+1}; D: col=lane&15,
//   row=(lane>>4)*4+reg.
__global__ __launch_bounds__(256) void gin_layer_kernel(const unsigned short* __restrict__ hb,
                                                        const int* __restrict__ off,
                                                        const int* __restrict__ csr,
                                                        const unsigned short* __restrict__ wb_hi,
                                                        const unsigned short* __restrict__ wb_lo,
                                                        const float* __restrict__ b,
                                                        unsigned short* __restrict__ hbout) {
  __shared__ unsigned atile[16 * 64];  // 4 KB, swizzled
  const int wid = threadIdx.x >> 6;
  const int lane = threadIdx.x & 63;
  const int base_m = blockIdx.x * 16;
  #pragma unroll
  for (int i = 0; i < 4; ++i) {
    const int r = wid * 4 + i;
    const int node = base_m + r;
    const unsigned su = *reinterpret_cast<const unsigned*>(hb + (size_t)node * D_HID + lane * 2);
    float sx0 = 2.f * bf_lo(su), sy0 = 2.f * bf_hi(su), sx1 = 0.f, sy1 = 0.f;
    const int e0 = off[node], e1 = off[node + 1];
    for (int base = e0; base < e1; base += 64) {
      int cnt = e1 - base; if (cnt > 64) cnt = 64;
      int vidx = (base + lane < e1) ? csr[base + lane] : 0;
      int j = 0;
      for (; j + 8 <= cnt; j += 8) {
        int i0 = __shfl(vidx, j, 64);
        int i1 = __shfl(vidx, j + 1, 64);
        int i2 = __shfl(vidx, j + 2, 64);
        int i3 = __shfl(vidx, j + 3, 64);
        int i4 = __shfl(vidx, j + 4, 64);
        int i5 = __shfl(vidx, j + 5, 64);
        int i6 = __shfl(vidx, j + 6, 64);
        int i7 = __shfl(vidx, j + 7, 64);
        unsigned u0 = *reinterpret_cast<const unsigned*>(hb + (size_t)i0 * D_HID + lane * 2);
        unsigned u1 = *reinterpret_cast<const unsigned*>(hb + (size_t)i1 * D_HID + lane * 2);
        unsigned u2 = *reinterpret_cast<const unsigned*>(hb + (size_t)i2 * D_HID + lane * 2);
        unsigned u3 = *reinterpret_cast<const unsigned*>(hb + (size_t)i3 * D_HID + lane * 2);
        unsigned u4 = *reinterpret_cast<const unsigned*>(hb + (size_t)i4 * D_HID + lane * 2);
        unsigned u5 = *reinterpret_cast<const unsigned*>(hb + (size_t)i5 * D_HID + lane * 2);
        unsigned u6 = *reinterpret_cast<const unsigned*>(hb + (size_t)i6 * D_HID + lane * 2);
        unsigned u7 = *reinterpret_cast<const unsigned*>(hb + (size_t)i7 * D_HID + lane * 2);
        sx0 += bf_lo(u0) + bf_lo(u1) + bf_lo(u2) + bf_lo(u3);
        sy0 += bf_hi(u0) + bf_hi(u1) + bf_hi(u2) + bf_hi(u3);
        sx1 += bf_lo(u4) + bf_lo(u5) + bf_lo(u6) + bf_lo(u7);
        sy1 += bf_hi(u4) + bf_hi(u5) + bf_hi(u6) + bf_hi(u7);
      }
      for (; j < cnt; ++j) {
        int i0 = __shfl(vidx, j, 64);
        unsigned u0 = *reinterpret_cast<const unsigned*>(hb + (size_t)i0 * D_HID + lane * 2);
        sx0 += bf_lo(u0); sy0 += bf_hi(u0);
      }
    }
    atile[r * 64 + (lane ^ ((r & 7) << 2))] = pack_bf16(sx0 + sx1, sy0 + sy1);
  }
  __syncthreads();
  const int l15 = lane & 15;
  const int lg = lane >> 4;
  bf16x8 a[4];
  #pragma unroll
  for (int kt = 0; kt < 4; ++kt) {
    const int u32off = l15 * 64 + ((kt * 16 + lg * 4) ^ ((l15 & 7) << 2));
    a[kt] = *reinterpret_cast<const bf16x8*>(&atile[u32off]);
  }
  #pragma unroll
  for (int q = 0; q < 2; ++q) {
    const int nt = wid * 2 + q;
    f32x4 acc = {0.f, 0.f, 0.f, 0.f};
    #pragma unroll
    for (int kt = 0; kt < 4; ++kt) {
      const int toff = (nt * 4 + kt) * 512 + lane * 8;
      bf16x8 bh = *reinterpret_cast<const bf16x8*>(wb_hi + toff);
      bf16x8 bl = *reinterpret_cast<const bf16x8*>(wb_lo + toff);
      acc = __builtin_amdgcn_mfma_f32_16x16x32_bf16(a[kt], bh, acc, 0, 0, 0);
      acc = __builtin_amdgcn_mfma_f32_16x16x32_bf16(a[kt], bl, acc, 0, 0, 0);
    }
    const int col = nt * 16 + l15;
    const float bcol = b[col];
    #pragma unroll
    for (int i = 0; i < 4; ++i) {
      const int node = base_m + lg * 4 + i;
      hbout[(size_t)node * D_HID + col] = (unsigned short)bf16_rn(acc[i] + bcol);
    }
  }
}

// single fused pool over all 6 feature buffers
__global__ __launch_bounds__(256) void pool6_kernel(const unsigned short* __restrict__ h0,
                                                    const unsigned short* __restrict__ h1,
                                                    const unsigned short* __restrict__ h2,
                                                    const unsigned short* __restrict__ h3,
                                                    const unsigned short* __restrict__ h4,
                                                    const unsigned short* __restrict__ h5,
                                                    const int* __restrict__ goff,
                                                    float* __restrict__ out) {
  const int g = blockIdx.x * 8 + (threadIdx.x >> 5);
  const int t = threadIdx.x & 31;
  if (g >= N_GRAPHS) return;
  const int n0 = goff[g], n1 = goff[g + 1];
  float4 s0 = {0,0,0,0}, s1 = {0,0,0,0}, s2 = {0,0,0,0};
  float4 s3 = {0,0,0,0}, s4 = {0,0,0,0}, s5 = {0,0,0,0};
  for (int n = n0; n < n1; ++n) {
    const size_t o = (size_t)n * D_HID + t * 4;
    uint2 v0 = *reinterpret_cast<const uint2*>(h0 + o);
    uint2 v1 = *reinterpret_cast<const uint2*>(h1 + o);
    uint2 v2 = *reinterpret_cast<const uint2*>(h2 + o);
    uint2 v3 = *reinterpret_cast<const uint2*>(h3 + o);
    uint2 v4 = *reinterpret_cast<const uint2*>(h4 + o);
    uint2 v5 = *reinterpret_cast<const uint2*>(h5 + o);
    s0.x += bf_lo(v0.x); s0.y += bf_hi(v0.x); s0.z += bf_lo(v0.y); s0.w += bf_hi(v0.y);
    s1.x += bf_lo(v1.x); s1.y += bf_hi(v1.x); s1.z += bf_lo(v1.y); s1.w += bf_hi(v1.y);
    s2.x += bf_lo(v2.x); s2.y += bf_hi(v2.x); s2.z += bf_lo(v2.y); s2.w += bf_hi(v2.y);
    s3.x += bf_lo(v3.x); s3.y += bf_hi(v3.x); s3.z += bf_lo(v3.y); s3.w += bf_hi(v3.y);
    s4.x += bf_lo(v4.x); s4.y += bf_hi(v4.x); s4.z += bf_lo(v4.y); s4.w += bf_hi(v4.y);
    s5.x += bf_lo(v5.x); s5.y += bf_hi(v5.x); s5.z += bf_lo(v5.y); s5.w += bf_hi(v5.y);
  }
  float* ob = out + (size_t)g * ((N_LAYERS + 1) * D_HID) + t * 4;
  *reinterpret_cast<float4*>(ob + 0 * D_HID) = s0;
  *reinterpret_cast<float4*>(ob + 1 * D_HID) = s1;
  *reinterpret_cast<float4*>(ob + 2 * D_HID) = s2;
  *reinterpret_cast<float4*>(ob + 3 * D_HID) = s3;
  *reinterpret_cast<float4*>(ob + 4 * D_HID) = s4;
  *reinterpret_cast<float4*>(ob + 5 * D_HID) = s5;
}

// ---------------- launch ----------------

extern "C" void kernel_launch(void* const* d_in, const int* in_sizes, int n_in,
                              void* d_out, int out_size, void* d_ws, size_t ws_size,
                              hipStream_t stream) {
  const float* x       = (const float*)d_in[0];
  const int*   edges   = (const int*)d_in[1];
  const int*   src     = edges;
  const int*   dst     = edges + N_EDGES;
  const int*   batch   = (const int*)d_in[2];
  const float* W_embed = (const float*)d_in[3];
  const float* Ws      = (const float*)d_in[4];
  const float* bs      = (const float*)d_in[5];
  float* out = (float*)d_out;

  const size_t HSZ = (size_t)N_NODES * D_HID;
  unsigned short* hb[N_LAYERS + 1];
  hb[0] = (unsigned short*)d_ws;
  for (int l = 1; l <= N_LAYERS; ++l) hb[l] = hb[l - 1] + HSZ;
  unsigned short* wb_hi = hb[N_LAYERS] + HSZ;                 // 5*16384 bf16
  unsigned short* wb_lo = wb_hi + (size_t)N_LAYERS * 16384;   // 5*16384 bf16
  unsigned long long* aux = (unsigned long long*)(wb_lo + (size_t)N_LAYERS * 16384); // E u64
  int*   off    = (int*)(aux + N_EDGES);                      // N+1
  int*   bcount = off + (N_NODES + 1);                        // 256
  int*   bbase  = bcount + NBUCK;                             // 257
  int*   gcur   = bbase + (NBUCK + 1);                        // 256
  int*   csr    = gcur + NBUCK;                               // E
  int*   goff   = csr + N_EDGES;                              // G+1

  // bucketed CSR build (edge list is layer-invariant)
  zero_int_kernel<<<1, 256, 0, stream>>>(bcount, NBUCK);
  bucket_count_kernel<<<NCHUNKS, 256, 0, stream>>>(dst, bcount);
  bucket_scan_kernel<<<1, NBUCK, 0, stream>>>(bcount, bbase, gcur);
  bucket_scatter_kernel<<<NCHUNKS, 256, 0, stream>>>(src, dst, gcur, aux);
  bucket_csr_kernel<<<NBUCK, 256, 0, stream>>>(aux, bbase, off, csr);
  graph_off_kernel<<<(N_GRAPHS + 1 + 255) / 256, 256, 0, stream>>>(batch, goff);

  // W packing for MFMA
  pack_w_kernel<<<(N_LAYERS * 16384 + 255) / 256, 256, 0, stream>>>(Ws, wb_hi, wb_lo);

  // embedding
  embed_kernel<<<(N_NODES + 63) / 64, 256, 0, stream>>>(x, W_embed, hb[0]);

  // fused gather+gemm layers
  for (int l = 0; l < N_LAYERS; ++l) {
    gin_layer_kernel<<<N_NODES / 16, 256, 0, stream>>>(hb[l], off, csr,
                                                       wb_hi + (size_t)l * 16384,
                                                       wb_lo + (size_t)l * 16384,
                                                       bs + (size_t)l * D_HID, hb[l + 1]);
  }

  // single fused pool of all 6 features
  pool6_kernel<<<N_GRAPHS / 8, 256, 0, stream>>>(hb[0], hb[1], hb[2], hb[3], hb[4], hb[5],
                                                 goff, out);
}

// Round 8
// 279.014 us; speedup vs baseline: 3.0297x; 1.0694x over previous
//
#include <hip/hip_runtime.h>

#define N_NODES 50000
#define N_EDGES 800000
#define N_GRAPHS 1024
#define N_LAYERS 5
#define D_IN 32
#define D_HID 128

#define NBUCK 256
#define BUCK_NODES 196   // ceil(N_NODES/NBUCK)
#define BUCK_CAP 4096    // LDS csr capacity per bucket (mean ~3125)
#define CHUNK 4096
#define NCHUNKS ((N_EDGES + CHUNK - 1) / CHUNK)  // 196

typedef __attribute__((ext_vector_type(8))) short bf16x8;
typedef __attribute__((ext_vector_type(4))) float f32x4;

// ---------------- bf16 helpers ----------------

__device__ __forceinline__ float bf_lo(unsigned u) { return __uint_as_float(u << 16); }
__device__ __forceinline__ float bf_hi(unsigned u) { return __uint_as_float(u & 0xffff0000u); }
__device__ __forceinline__ unsigned bf16_rn(float f) {
  unsigned u = __float_as_uint(f);
  return (u + 0x7fffu + ((u >> 16) & 1u)) >> 16;  // round-to-nearest-even
}
__device__ __forceinline__ unsigned pack_bf16(float a, float b) {
  return bf16_rn(a) | (bf16_rn(b) << 16);
}

// ---------------- bucketed CSR build ----------------

__global__ void zero_int_kernel(int* __restrict__ p, int n) {
  int i = blockIdx.x * blockDim.x + threadIdx.x;
  if (i < n) p[i] = 0;
}

__global__ __launch_bounds__(256) void bucket_count_kernel(const int* __restrict__ dst,
                                                           int* __restrict__ bcount) {
  __shared__ int cnt[NBUCK];
  for (int i = threadIdx.x; i < NBUCK; i += 256) cnt[i] = 0;
  __syncthreads();
  const int cb = blockIdx.x * CHUNK;
  const int end = (cb + CHUNK < N_EDGES) ? cb + CHUNK : N_EDGES;
  for (int e = cb + threadIdx.x; e < end; e += 256)
    atomicAdd(&cnt[dst[e] / BUCK_NODES], 1);
  __syncthreads();
  for (int i = threadIdx.x; i < NBUCK; i += 256)
    if (cnt[i]) atomicAdd(&bcount[i], cnt[i]);
}

__global__ __launch_bounds__(256) void bucket_scan_kernel(const int* __restrict__ bcount,
                                                          int* __restrict__ bbase,
                                                          int* __restrict__ gcur) {
  __shared__ int s[NBUCK];
  const int t = threadIdx.x;
  const int v0 = bcount[t];
  s[t] = v0;
  __syncthreads();
  #pragma unroll
  for (int d = 1; d < NBUCK; d <<= 1) {
    int v = (t >= d) ? s[t - d] : 0;
    __syncthreads();
    s[t] += v;
    __syncthreads();
  }
  bbase[t + 1] = s[t];
  if (t == 0) bbase[0] = 0;
  gcur[t] = s[t] - v0;  // exclusive prefix
}

__global__ __launch_bounds__(256) void bucket_scatter_kernel(const int* __restrict__ src,
                                                             const int* __restrict__ dst,
                                                             int* __restrict__ gcur,
                                                             unsigned long long* __restrict__ aux) {
  __shared__ int cnt[NBUCK];
  __shared__ int base_[NBUCK];
  __shared__ int cur[NBUCK];
  for (int i = threadIdx.x; i < NBUCK; i += 256) cnt[i] = 0;
  __syncthreads();
  const int cb = blockIdx.x * CHUNK;
  const int end = (cb + CHUNK < N_EDGES) ? cb + CHUNK : N_EDGES;
  for (int e = cb + threadIdx.x; e < end; e += 256)
    atomicAdd(&cnt[dst[e] / BUCK_NODES], 1);
  __syncthreads();
  for (int i = threadIdx.x; i < NBUCK; i += 256) {
    base_[i] = cnt[i] ? atomicAdd(&gcur[i], cnt[i]) : 0;
    cur[i] = 0;
  }
  __syncthreads();
  for (int e = cb + threadIdx.x; e < end; e += 256) {
    const int d = dst[e];
    const int b = d / BUCK_NODES;
    const int p = base_[b] + atomicAdd(&cur[b], 1);
    aux[p] = ((unsigned long long)(unsigned)d << 32) | (unsigned)src[e];
  }
}

__global__ __launch_bounds__(256) void bucket_csr_kernel(const unsigned long long* __restrict__ aux,
                                                         const int* __restrict__ bbase,
                                                         int* __restrict__ off,
                                                         int* __restrict__ csr) {
  __shared__ int sdeg[NBUCK];
  __shared__ int sscan[NBUCK];
  __shared__ int scur[NBUCK];
  __shared__ int lcsr[BUCK_CAP];
  const int b = blockIdx.x, t = threadIdx.x;
  const int e0 = bbase[b], e1 = bbase[b + 1];
  const int n0 = b * BUCK_NODES;
  const int nN = (N_NODES - n0 < BUCK_NODES) ? (N_NODES - n0) : BUCK_NODES;
  sdeg[t] = 0;
  __syncthreads();
  for (int i = e0 + t; i < e1; i += 256)
    atomicAdd(&sdeg[(int)(aux[i] >> 32) - n0], 1);
  __syncthreads();
  sscan[t] = sdeg[t];
  __syncthreads();
  #pragma unroll
  for (int d = 1; d < NBUCK; d <<= 1) {
    int v = (t >= d) ? sscan[t - d] : 0;
    __syncthreads();
    sscan[t] += v;
    __syncthreads();
  }
  const int exc_t = sscan[t] - sdeg[t];
  __syncthreads();
  sscan[t] = exc_t;
  scur[t] = 0;
  if (t < nN) off[n0 + t] = e0 + exc_t;
  if (b == NBUCK - 1 && t == 0) off[N_NODES] = e1;
  __syncthreads();
  for (int i = e0 + t; i < e1; i += 256) {
    const unsigned long long v = aux[i];
    const int d = (int)(v >> 32) - n0;
    const int pos = sscan[d] + atomicAdd(&scur[d], 1);
    const int s = (int)(unsigned)(v & 0xffffffffu);
    if (pos < BUCK_CAP) lcsr[pos] = s;
    else csr[e0 + pos] = s;  // overflow guard (statistically never)
  }
  __syncthreads();
  const int cntAll = e1 - e0;
  const int lim = (cntAll < BUCK_CAP) ? cntAll : BUCK_CAP;
  for (int i = t; i < lim; i += 256) csr[e0 + i] = lcsr[i];
}

// goff[g] = lower_bound(batch, g); batch is sorted
__global__ void graph_off_kernel(const int* __restrict__ batch, int* __restrict__ goff) {
  int g = blockIdx.x * blockDim.x + threadIdx.x;
  if (g <= N_GRAPHS) {
    int lo = 0, hi = N_NODES;
    while (lo < hi) { int mid = (lo + hi) >> 1; if (batch[mid] < g) lo = mid + 1; else hi = mid; }
    goff[g] = lo;
  }
}

// ---------------- W packing for MFMA ----------------
// B-frag for v_mfma_f32_16x16x32_bf16: lane l, elem i = B[kt*32+(l>>4)*8+i][nt*16+(l&15)]
// hi/lo split keeps weights ~f32-exact.
__global__ void pack_w_kernel(const float* __restrict__ Ws,
                              unsigned short* __restrict__ wb_hi,
                              unsigned short* __restrict__ wb_lo) {
  int idx = blockIdx.x * blockDim.x + threadIdx.x;
  if (idx >= N_LAYERS * 16384) return;
  int layer = idx >> 14;
  int r = idx & 16383;
  int t = r >> 9;
  int lane = (r >> 3) & 63;
  int i = r & 7;
  int nt = t >> 2, kt = t & 3;
  int k = kt * 32 + (lane >> 4) * 8 + i;
  int c = nt * 16 + (lane & 15);
  float f = Ws[(size_t)layer * 16384 + k * D_HID + c];
  unsigned short h = (unsigned short)bf16_rn(f);
  float hf = __uint_as_float(((unsigned)h) << 16);
  unsigned short l = (unsigned short)bf16_rn(f - hf);
  wb_hi[idx] = h;
  wb_lo[idx] = l;
}

// ---------------- compute ----------------

// hb = bf16(x @ W_embed)
__global__ __launch_bounds__(256) void embed_kernel(const float* __restrict__ x,
                                                    const float* __restrict__ W,
                                                    unsigned short* __restrict__ hb) {
  __shared__ float Wl[D_IN * D_HID];
  __shared__ float xl[64 * D_IN];
  for (int i = threadIdx.x; i < D_IN * D_HID; i += 256) Wl[i] = W[i];
  const int base = blockIdx.x * 64;
  const int nThis = (base + 64 <= N_NODES) ? 64 : (N_NODES - base);
  const float4* x4 = reinterpret_cast<const float4*>(x + (size_t)base * D_IN);
  for (int i = threadIdx.x; i < nThis * (D_IN / 4); i += 256)
    reinterpret_cast<float4*>(xl)[i] = x4[i];
  __syncthreads();
  const int c2 = (threadIdx.x & 63) * 2;
  const int sub = threadIdx.x >> 6;
  for (int r = sub; r < nThis; r += 4) {
    float s0 = 0.f, s1 = 0.f;
    #pragma unroll
    for (int k = 0; k < D_IN; ++k) {
      float xv = xl[r * D_IN + k];
      s0 += xv * Wl[k * D_HID + c2];
      s1 += xv * Wl[k * D_HID + c2 + 1];
    }
    *reinterpret_cast<unsigned*>(hb + (size_t)(base + r) * D_HID + c2) = pack_bf16(s0, s1);
  }
}

// Fused GIN layer: block = 4 waves = 16 nodes.
// Gather phase (quarter-wave): quarter q of wave w owns row r = w*4+q; each of its
//   16 lanes covers 16B (8 bf16 cols). One load instr = 4 edges (one per quarter,
//   4x256B coalesced). Ragged degrees: sc in {0,1} FMA predication; clamped idx.
// Gemm phase: A-frag via swizzled ds_read_b128 (layout identical to proven R5/R6);
//   each wave computes nt = {2w, 2w+1}; D: col=lane&15, row=(lane>>4)*4+reg.
__global__ __launch_bounds__(256, 4) void gin_layer_kernel(const unsigned short* __restrict__ hb,
                                                           const int* __restrict__ off,
                                                           const int* __restrict__ csr,
                                                           const unsigned short* __restrict__ wb_hi,
                                                           const unsigned short* __restrict__ wb_lo,
                                                           const float* __restrict__ b,
                                                           unsigned short* __restrict__ hbout) {
  __shared__ unsigned atile[16 * 64];  // 4 KB, swizzled
  const int wid = threadIdx.x >> 6;
  const int lane = threadIdx.x & 63;
  const int base_m = blockIdx.x * 16;
  const int q = lane >> 4;       // quarter 0..3
  const int l16 = lane & 15;
  const int r = wid * 4 + q;     // row 0..15 within block
  const int node = base_m + r;

  const int e0 = off[node], e1 = off[node + 1];
  const int deg = e1 - e0;
  // wave-wide max degree (deg uniform within each quarter)
  int md = deg;
  md = max(md, __shfl_xor(md, 16, 64));
  md = max(md, __shfl_xor(md, 32, 64));

  // self term: 2*h[node]
  float s[8];
  {
    const uint4 su = *reinterpret_cast<const uint4*>(hb + (size_t)node * D_HID + l16 * 8);
    const unsigned* sw = reinterpret_cast<const unsigned*>(&su);
    #pragma unroll
    for (int i = 0; i < 4; ++i) {
      s[2 * i]     = 2.f * bf_lo(sw[i]);
      s[2 * i + 1] = 2.f * bf_hi(sw[i]);
    }
  }

  for (int bb = 0; bb < md; bb += 16) {
    const int epos = e0 + bb + l16;
    const int vidx = (epos < e1) ? csr[epos] : 0;
    const int cntq = deg - bb;  // may be <= 0 for this quarter
    #pragma unroll
    for (int j = 0; j < 16; ++j) {
      const int idx = __shfl(vidx, (lane & 48) + j, 64);
      const float sc = (j < cntq) ? 1.f : 0.f;
      const uint4 u = *reinterpret_cast<const uint4*>(hb + (size_t)idx * D_HID + l16 * 8);
      const unsigned* uw = reinterpret_cast<const unsigned*>(&u);
      #pragma unroll
      for (int i = 0; i < 4; ++i) {
        s[2 * i]     += sc * bf_lo(uw[i]);
        s[2 * i + 1] += sc * bf_hi(uw[i]);
      }
    }
  }

  // pack 8 f32 -> 4 u32 and store as one swizzled ds_write_b128
  {
    uint4 pk;
    unsigned* pw = reinterpret_cast<unsigned*>(&pk);
    #pragma unroll
    for (int i = 0; i < 4; ++i) pw[i] = pack_bf16(s[2 * i], s[2 * i + 1]);
    const int wbase = (l16 * 4) ^ ((r & 7) << 2);  // aligned 4-word base, XOR preserves alignment
    *reinterpret_cast<uint4*>(&atile[r * 64 + wbase]) = pk;
  }
  __syncthreads();

  const int l15 = lane & 15;
  const int lg = lane >> 4;
  bf16x8 a[4];
  #pragma unroll
  for (int kt = 0; kt < 4; ++kt) {
    const int u32off = l15 * 64 + ((kt * 16 + lg * 4) ^ ((l15 & 7) << 2));
    a[kt] = *reinterpret_cast<const bf16x8*>(&atile[u32off]);
  }
  #pragma unroll
  for (int qq = 0; qq < 2; ++qq) {
    const int nt = wid * 2 + qq;
    f32x4 acc = {0.f, 0.f, 0.f, 0.f};
    #pragma unroll
    for (int kt = 0; kt < 4; ++kt) {
      const int toff = (nt * 4 + kt) * 512 + lane * 8;
      bf16x8 bh = *reinterpret_cast<const bf16x8*>(wb_hi + toff);
      bf16x8 bl = *reinterpret_cast<const bf16x8*>(wb_lo + toff);
      acc = __builtin_amdgcn_mfma_f32_16x16x32_bf16(a[kt], bh, acc, 0, 0, 0);
      acc = __builtin_amdgcn_mfma_f32_16x16x32_bf16(a[kt], bl, acc, 0, 0, 0);
    }
    const int col = nt * 16 + l15;
    const float bcol = b[col];
    #pragma unroll
    for (int i = 0; i < 4; ++i) {
      const int onode = base_m + lg * 4 + i;
      hbout[(size_t)onode * D_HID + col] = (unsigned short)bf16_rn(acc[i] + bcol);
    }
  }
}

// single fused pool over all 6 feature buffers
__global__ __launch_bounds__(256) void pool6_kernel(const unsigned short* __restrict__ h0,
                                                    const unsigned short* __restrict__ h1,
                                                    const unsigned short* __restrict__ h2,
                                                    const unsigned short* __restrict__ h3,
                                                    const unsigned short* __restrict__ h4,
                                                    const unsigned short* __restrict__ h5,
                                                    const int* __restrict__ goff,
                                                    float* __restrict__ out) {
  const int g = blockIdx.x * 8 + (threadIdx.x >> 5);
  const int t = threadIdx.x & 31;
  if (g >= N_GRAPHS) return;
  const int n0 = goff[g], n1 = goff[g + 1];
  float4 s0 = {0,0,0,0}, s1 = {0,0,0,0}, s2 = {0,0,0,0};
  float4 s3 = {0,0,0,0}, s4 = {0,0,0,0}, s5 = {0,0,0,0};
  for (int n = n0; n < n1; ++n) {
    const size_t o = (size_t)n * D_HID + t * 4;
    uint2 v0 = *reinterpret_cast<const uint2*>(h0 + o);
    uint2 v1 = *reinterpret_cast<const uint2*>(h1 + o);
    uint2 v2 = *reinterpret_cast<const uint2*>(h2 + o);
    uint2 v3 = *reinterpret_cast<const uint2*>(h3 + o);
    uint2 v4 = *reinterpret_cast<const uint2*>(h4 + o);
    uint2 v5 = *reinterpret_cast<const uint2*>(h5 + o);
    s0.x += bf_lo(v0.x); s0.y += bf_hi(v0.x); s0.z += bf_lo(v0.y); s0.w += bf_hi(v0.y);
    s1.x += bf_lo(v1.x); s1.y += bf_hi(v1.x); s1.z += bf_lo(v1.y); s1.w += bf_hi(v1.y);
    s2.x += bf_lo(v2.x); s2.y += bf_hi(v2.x); s2.z += bf_lo(v2.y); s2.w += bf_hi(v2.y);
    s3.x += bf_lo(v3.x); s3.y += bf_hi(v3.x); s3.z += bf_lo(v3.y); s3.w += bf_hi(v3.y);
    s4.x += bf_lo(v4.x); s4.y += bf_hi(v4.x); s4.z += bf_lo(v4.y); s4.w += bf_hi(v4.y);
    s5.x += bf_lo(v5.x); s5.y += bf_hi(v5.x); s5.z += bf_lo(v5.y); s5.w += bf_hi(v5.y);
  }
  float* ob = out + (size_t)g * ((N_LAYERS + 1) * D_HID) + t * 4;
  *reinterpret_cast<float4*>(ob + 0 * D_HID) = s0;
  *reinterpret_cast<float4*>(ob + 1 * D_HID) = s1;
  *reinterpret_cast<float4*>(ob + 2 * D_HID) = s2;
  *reinterpret_cast<float4*>(ob + 3 * D_HID) = s3;
  *reinterpret_cast<float4*>(ob + 4 * D_HID) = s4;
  *reinterpret_cast<float4*>(ob + 5 * D_HID) = s5;
}

// ---------------- launch ----------------

extern "C" void kernel_launch(void* const* d_in, const int* in_sizes, int n_in,
                              void* d_out, int out_size, void* d_ws, size_t ws_size,
                              hipStream_t stream) {
  const float* x       = (const float*)d_in[0];
  const int*   edges   = (const int*)d_in[1];
  const int*   src     = edges;
  const int*   dst     = edges + N_EDGES;
  const int*   batch   = (const int*)d_in[2];
  const float* W_embed = (const float*)d_in[3];
  const float* Ws      = (const float*)d_in[4];
  const float* bs      = (const float*)d_in[5];
  float* out = (float*)d_out;

  const size_t HSZ = (size_t)N_NODES * D_HID;
  unsigned short* hb[N_LAYERS + 1];
  hb[0] = (unsigned short*)d_ws;
  for (int l = 1; l <= N_LAYERS; ++l) hb[l] = hb[l - 1] + HSZ;
  unsigned short* wb_hi = hb[N_LAYERS] + HSZ;                 // 5*16384 bf16
  unsigned short* wb_lo = wb_hi + (size_t)N_LAYERS * 16384;   // 5*16384 bf16
  unsigned long long* aux = (unsigned long long*)(wb_lo + (size_t)N_LAYERS * 16384); // E u64
  int*   off    = (int*)(aux + N_EDGES);                      // N+1
  int*   bcount = off + (N_NODES + 1);                        // 256
  int*   bbase  = bcount + NBUCK;                             // 257
  int*   gcur   = bbase + (NBUCK + 1);                        // 256
  int*   csr    = gcur + NBUCK;                               // E
  int*   goff   = csr + N_EDGES;                              // G+1

  // bucketed CSR build (edge list is layer-invariant)
  zero_int_kernel<<<1, 256, 0, stream>>>(bcount, NBUCK);
  bucket_count_kernel<<<NCHUNKS, 256, 0, stream>>>(dst, bcount);
  bucket_scan_kernel<<<1, NBUCK, 0, stream>>>(bcount, bbase, gcur);
  bucket_scatter_kernel<<<NCHUNKS, 256, 0, stream>>>(src, dst, gcur, aux);
  bucket_csr_kernel<<<NBUCK, 256, 0, stream>>>(aux, bbase, off, csr);
  graph_off_kernel<<<(N_GRAPHS + 1 + 255) / 256, 256, 0, stream>>>(batch, goff);

  // W packing for MFMA
  pack_w_kernel<<<(N_LAYERS * 16384 + 255) / 256, 256, 0, stream>>>(Ws, wb_hi, wb_lo);

  // embedding
  embed_kernel<<<(N_NODES + 63) / 64, 256, 0, stream>>>(x, W_embed, hb[0]);

  // fused gather+gemm layers
  for (int l = 0; l < N_LAYERS; ++l) {
    gin_layer_kernel<<<N_NODES / 16, 256, 0, stream>>>(hb[l], off, csr,
                                                       wb_hi + (size_t)l * 16384,
                                                       wb_lo + (size_t)l * 16384,
                                                       bs + (size_t)l * D_HID, hb[l + 1]);
  }

  // single fused pool of all 6 features
  pool6_kernel<<<N_GRAPHS / 8, 256, 0, stream>>>(hb[0], hb[1], hb[2], hb[3], hb[4], hb[5],
                                                 goff, out);
}

// Round 9
// 269.080 us; speedup vs baseline: 3.1416x; 1.0369x over previous
//
#include <hip/hip_runtime.h>

#define N_NODES 50000
#define N_EDGES 800000
#define N_GRAPHS 1024
#define N_LAYERS 5
#define D_IN 32
#define D_HID 128

#define NBUCK 256
#define BUCK_NODES 196   // ceil(N_NODES/NBUCK)
#define BUCK_CAP 4096    // LDS csr capacity per bucket (mean ~3125)
#define CHUNK 4096
#define NCHUNKS ((N_EDGES + CHUNK - 1) / CHUNK)  // 196

typedef __attribute__((ext_vector_type(8))) short bf16x8;
typedef __attribute__((ext_vector_type(4))) float f32x4;

// ---------------- bf16 helpers ----------------

__device__ __forceinline__ float bf_lo(unsigned u) { return __uint_as_float(u << 16); }
__device__ __forceinline__ float bf_hi(unsigned u) { return __uint_as_float(u & 0xffff0000u); }
__device__ __forceinline__ unsigned bf16_rn(float f) {
  unsigned u = __float_as_uint(f);
  return (u + 0x7fffu + ((u >> 16) & 1u)) >> 16;  // round-to-nearest-even
}
__device__ __forceinline__ unsigned pack_bf16(float a, float b) {
  return bf16_rn(a) | (bf16_rn(b) << 16);
}

// ---------------- bucketed CSR build ----------------

__global__ void zero_int_kernel(int* __restrict__ p, int n) {
  int i = blockIdx.x * blockDim.x + threadIdx.x;
  if (i < n) p[i] = 0;
}

__global__ __launch_bounds__(256) void bucket_count_kernel(const int* __restrict__ dst,
                                                           int* __restrict__ bcount) {
  __shared__ int cnt[NBUCK];
  for (int i = threadIdx.x; i < NBUCK; i += 256) cnt[i] = 0;
  __syncthreads();
  const int cb = blockIdx.x * CHUNK;
  const int end = (cb + CHUNK < N_EDGES) ? cb + CHUNK : N_EDGES;
  for (int e = cb + threadIdx.x; e < end; e += 256)
    atomicAdd(&cnt[dst[e] / BUCK_NODES], 1);
  __syncthreads();
  for (int i = threadIdx.x; i < NBUCK; i += 256)
    if (cnt[i]) atomicAdd(&bcount[i], cnt[i]);
}

__global__ __launch_bounds__(256) void bucket_scan_kernel(const int* __restrict__ bcount,
                                                          int* __restrict__ bbase,
                                                          int* __restrict__ gcur) {
  __shared__ int s[NBUCK];
  const int t = threadIdx.x;
  const int v0 = bcount[t];
  s[t] = v0;
  __syncthreads();
  #pragma unroll
  for (int d = 1; d < NBUCK; d <<= 1) {
    int v = (t >= d) ? s[t - d] : 0;
    __syncthreads();
    s[t] += v;
    __syncthreads();
  }
  bbase[t + 1] = s[t];
  if (t == 0) bbase[0] = 0;
  gcur[t] = s[t] - v0;  // exclusive prefix
}

__global__ __launch_bounds__(256) void bucket_scatter_kernel(const int* __restrict__ src,
                                                             const int* __restrict__ dst,
                                                             int* __restrict__ gcur,
                                                             unsigned long long* __restrict__ aux) {
  __shared__ int cnt[NBUCK];
  __shared__ int base_[NBUCK];
  __shared__ int cur[NBUCK];
  for (int i = threadIdx.x; i < NBUCK; i += 256) cnt[i] = 0;
  __syncthreads();
  const int cb = blockIdx.x * CHUNK;
  const int end = (cb + CHUNK < N_EDGES) ? cb + CHUNK : N_EDGES;
  for (int e = cb + threadIdx.x; e < end; e += 256)
    atomicAdd(&cnt[dst[e] / BUCK_NODES], 1);
  __syncthreads();
  for (int i = threadIdx.x; i < NBUCK; i += 256) {
    base_[i] = cnt[i] ? atomicAdd(&gcur[i], cnt[i]) : 0;
    cur[i] = 0;
  }
  __syncthreads();
  for (int e = cb + threadIdx.x; e < end; e += 256) {
    const int d = dst[e];
    const int b = d / BUCK_NODES;
    const int p = base_[b] + atomicAdd(&cur[b], 1);
    aux[p] = ((unsigned long long)(unsigned)d << 32) | (unsigned)src[e];
  }
}

__global__ __launch_bounds__(256) void bucket_csr_kernel(const unsigned long long* __restrict__ aux,
                                                         const int* __restrict__ bbase,
                                                         int* __restrict__ off,
                                                         int* __restrict__ csr) {
  __shared__ int sdeg[NBUCK];
  __shared__ int sscan[NBUCK];
  __shared__ int scur[NBUCK];
  __shared__ int lcsr[BUCK_CAP];
  const int b = blockIdx.x, t = threadIdx.x;
  const int e0 = bbase[b], e1 = bbase[b + 1];
  const int n0 = b * BUCK_NODES;
  const int nN = (N_NODES - n0 < BUCK_NODES) ? (N_NODES - n0) : BUCK_NODES;
  sdeg[t] = 0;
  __syncthreads();
  for (int i = e0 + t; i < e1; i += 256)
    atomicAdd(&sdeg[(int)(aux[i] >> 32) - n0], 1);
  __syncthreads();
  sscan[t] = sdeg[t];
  __syncthreads();
  #pragma unroll
  for (int d = 1; d < NBUCK; d <<= 1) {
    int v = (t >= d) ? sscan[t - d] : 0;
    __syncthreads();
    sscan[t] += v;
    __syncthreads();
  }
  const int exc_t = sscan[t] - sdeg[t];
  __syncthreads();
  sscan[t] = exc_t;
  scur[t] = 0;
  if (t < nN) off[n0 + t] = e0 + exc_t;
  if (b == NBUCK - 1 && t == 0) off[N_NODES] = e1;
  __syncthreads();
  for (int i = e0 + t; i < e1; i += 256) {
    const unsigned long long v = aux[i];
    const int d = (int)(v >> 32) - n0;
    const int pos = sscan[d] + atomicAdd(&scur[d], 1);
    const int s = (int)(unsigned)(v & 0xffffffffu);
    if (pos < BUCK_CAP) lcsr[pos] = s;
    else csr[e0 + pos] = s;  // overflow guard (statistically never)
  }
  __syncthreads();
  const int cntAll = e1 - e0;
  const int lim = (cntAll < BUCK_CAP) ? cntAll : BUCK_CAP;
  for (int i = t; i < lim; i += 256) csr[e0 + i] = lcsr[i];
}

// goff[g] = lower_bound(batch, g); batch is sorted
__global__ void graph_off_kernel(const int* __restrict__ batch, int* __restrict__ goff) {
  int g = blockIdx.x * blockDim.x + threadIdx.x;
  if (g <= N_GRAPHS) {
    int lo = 0, hi = N_NODES;
    while (lo < hi) { int mid = (lo + hi) >> 1; if (batch[mid] < g) lo = mid + 1; else hi = mid; }
    goff[g] = lo;
  }
}

// ---------------- W packing for MFMA ----------------
// B-frag for v_mfma_f32_16x16x32_bf16: lane l, elem i = B[kt*32+(l>>4)*8+i][nt*16+(l&15)]
// hi/lo split keeps weights ~f32-exact.
__global__ void pack_w_kernel(const float* __restrict__ Ws,
                              unsigned short* __restrict__ wb_hi,
                              unsigned short* __restrict__ wb_lo) {
  int idx = blockIdx.x * blockDim.x + threadIdx.x;
  if (idx >= N_LAYERS * 16384) return;
  int layer = idx >> 14;
  int r = idx & 16383;
  int t = r >> 9;
  int lane = (r >> 3) & 63;
  int i = r & 7;
  int nt = t >> 2, kt = t & 3;
  int k = kt * 32 + (lane >> 4) * 8 + i;
  int c = nt * 16 + (lane & 15);
  float f = Ws[(size_t)layer * 16384 + k * D_HID + c];
  unsigned short h = (unsigned short)bf16_rn(f);
  float hf = __uint_as_float(((unsigned)h) << 16);
  unsigned short l = (unsigned short)bf16_rn(f - hf);
  wb_hi[idx] = h;
  wb_lo[idx] = l;
}

// ---------------- compute ----------------

// hb = bf16(x @ W_embed)
__global__ __launch_bounds__(256) void embed_kernel(const float* __restrict__ x,
                                                    const float* __restrict__ W,
                                                    unsigned short* __restrict__ hb) {
  __shared__ float Wl[D_IN * D_HID];
  __shared__ float xl[64 * D_IN];
  for (int i = threadIdx.x; i < D_IN * D_HID; i += 256) Wl[i] = W[i];
  const int base = blockIdx.x * 64;
  const int nThis = (base + 64 <= N_NODES) ? 64 : (N_NODES - base);
  const float4* x4 = reinterpret_cast<const float4*>(x + (size_t)base * D_IN);
  for (int i = threadIdx.x; i < nThis * (D_IN / 4); i += 256)
    reinterpret_cast<float4*>(xl)[i] = x4[i];
  __syncthreads();
  const int c2 = (threadIdx.x & 63) * 2;
  const int sub = threadIdx.x >> 6;
  for (int r = sub; r < nThis; r += 4) {
    float s0 = 0.f, s1 = 0.f;
    #pragma unroll
    for (int k = 0; k < D_IN; ++k) {
      float xv = xl[r * D_IN + k];
      s0 += xv * Wl[k * D_HID + c2];
      s1 += xv * Wl[k * D_HID + c2 + 1];
    }
    *reinterpret_cast<unsigned*>(hb + (size_t)(base + r) * D_HID + c2) = pack_bf16(s0, s1);
  }
}

// Fused GIN layer: block = 4 waves = 16 nodes.
// Gather (quarter-wave): quarter q of wave w owns row r = w*4+q; each of its 16
//   lanes covers 16B (8 bf16 cols). Per-quarter divergent loop over its OWN deg
//   (uniform within quarter -> shfl sources stay active together); 8-deep
//   register-array load batching forces 8 loads in flight before accumulation.
// Gemm: A-frag via swizzled ds_read_b128 (proven R5/R6 layout); wave computes
//   nt = {2w, 2w+1}; D: col=lane&15, row=(lane>>4)*4+reg.
__global__ __launch_bounds__(256, 6) void gin_layer_kernel(const unsigned short* __restrict__ hb,
                                                           const int* __restrict__ off,
                                                           const int* __restrict__ csr,
                                                           const unsigned short* __restrict__ wb_hi,
                                                           const unsigned short* __restrict__ wb_lo,
                                                           const float* __restrict__ b,
                                                           unsigned short* __restrict__ hbout) {
  __shared__ unsigned atile[16 * 64];  // 4 KB, swizzled
  const int wid = threadIdx.x >> 6;
  const int lane = threadIdx.x & 63;
  const int base_m = blockIdx.x * 16;
  const int q = lane >> 4;       // quarter 0..3
  const int l16 = lane & 15;
  const int r = wid * 4 + q;     // row 0..15 within block
  const int node = base_m + r;

  const int e0 = off[node], e1 = off[node + 1];
  const int deg = e1 - e0;

  // self term: 2*h[node]
  float s[8];
  {
    const uint4 su = *reinterpret_cast<const uint4*>(hb + (size_t)node * D_HID + l16 * 8);
    const unsigned* sw = reinterpret_cast<const unsigned*>(&su);
    #pragma unroll
    for (int i = 0; i < 4; ++i) {
      s[2 * i]     = 2.f * bf_lo(sw[i]);
      s[2 * i + 1] = 2.f * bf_hi(sw[i]);
    }
  }

  // per-quarter loop: deg is uniform within the 16-lane quarter, so this
  // diverges only BETWEEN quarters; finished quarters are exec-masked and
  // stop issuing loads.
  for (int bb = 0; bb < deg; bb += 16) {
    const int epos = e0 + bb + l16;
    const int vidx = (epos < e1) ? csr[epos] : 0;
    #pragma unroll
    for (int half = 0; half < 2; ++half) {
      const int jb = half * 8;
      if (bb + jb < deg) {                 // quarter-uniform branch
        uint4 u[8];
        #pragma unroll
        for (int j = 0; j < 8; ++j) {
          const int idx = __shfl(vidx, (lane & 48) + jb + j, 64);
          u[j] = *reinterpret_cast<const uint4*>(hb + (size_t)idx * D_HID + l16 * 8);
        }
        const int rem = deg - bb - jb;
        #pragma unroll
        for (int j = 0; j < 8; ++j) {
          const float sc = (j < rem) ? 1.f : 0.f;
          const unsigned* uw = reinterpret_cast<const unsigned*>(&u[j]);
          #pragma unroll
          for (int i = 0; i < 4; ++i) {
            s[2 * i]     += sc * bf_lo(uw[i]);
            s[2 * i + 1] += sc * bf_hi(uw[i]);
          }
        }
      }
    }
  }

  // pack 8 f32 -> 4 u32 and store as one swizzled ds_write_b128
  {
    uint4 pk;
    unsigned* pw = reinterpret_cast<unsigned*>(&pk);
    #pragma unroll
    for (int i = 0; i < 4; ++i) pw[i] = pack_bf16(s[2 * i], s[2 * i + 1]);
    const int wbase = (l16 * 4) ^ ((r & 7) << 2);  // aligned 4-word base
    *reinterpret_cast<uint4*>(&atile[r * 64 + wbase]) = pk;
  }
  __syncthreads();

  const int l15 = lane & 15;
  const int lg = lane >> 4;
  bf16x8 a[4];
  #pragma unroll
  for (int kt = 0; kt < 4; ++kt) {
    const int u32off = l15 * 64 + ((kt * 16 + lg * 4) ^ ((l15 & 7) << 2));
    a[kt] = *reinterpret_cast<const bf16x8*>(&atile[u32off]);
  }
  #pragma unroll
  for (int qq = 0; qq < 2; ++qq) {
    const int nt = wid * 2 + qq;
    f32x4 acc = {0.f, 0.f, 0.f, 0.f};
    #pragma unroll
    for (int kt = 0; kt < 4; ++kt) {
      const int toff = (nt * 4 + kt) * 512 + lane * 8;
      bf16x8 bh = *reinterpret_cast<const bf16x8*>(wb_hi + toff);
      bf16x8 bl = *reinterpret_cast<const bf16x8*>(wb_lo + toff);
      acc = __builtin_amdgcn_mfma_f32_16x16x32_bf16(a[kt], bh, acc, 0, 0, 0);
      acc = __builtin_amdgcn_mfma_f32_16x16x32_bf16(a[kt], bl, acc, 0, 0, 0);
    }
    const int col = nt * 16 + l15;
    const float bcol = b[col];
    #pragma unroll
    for (int i = 0; i < 4; ++i) {
      const int onode = base_m + lg * 4 + i;
      hbout[(size_t)onode * D_HID + col] = (unsigned short)bf16_rn(acc[i] + bcol);
    }
  }
}

// single fused pool over all 6 feature buffers
__global__ __launch_bounds__(256) void pool6_kernel(const unsigned short* __restrict__ h0,
                                                    const unsigned short* __restrict__ h1,
                                                    const unsigned short* __restrict__ h2,
                                                    const unsigned short* __restrict__ h3,
                                                    const unsigned short* __restrict__ h4,
                                                    const unsigned short* __restrict__ h5,
                                                    const int* __restrict__ goff,
                                                    float* __restrict__ out) {
  const int g = blockIdx.x * 8 + (threadIdx.x >> 5);
  const int t = threadIdx.x & 31;
  if (g >= N_GRAPHS) return;
  const int n0 = goff[g], n1 = goff[g + 1];
  float4 s0 = {0,0,0,0}, s1 = {0,0,0,0}, s2 = {0,0,0,0};
  float4 s3 = {0,0,0,0}, s4 = {0,0,0,0}, s5 = {0,0,0,0};
  for (int n = n0; n < n1; ++n) {
    const size_t o = (size_t)n * D_HID + t * 4;
    uint2 v0 = *reinterpret_cast<const uint2*>(h0 + o);
    uint2 v1 = *reinterpret_cast<const uint2*>(h1 + o);
    uint2 v2 = *reinterpret_cast<const uint2*>(h2 + o);
    uint2 v3 = *reinterpret_cast<const uint2*>(h3 + o);
    uint2 v4 = *reinterpret_cast<const uint2*>(h4 + o);
    uint2 v5 = *reinterpret_cast<const uint2*>(h5 + o);
    s0.x += bf_lo(v0.x); s0.y += bf_hi(v0.x); s0.z += bf_lo(v0.y); s0.w += bf_hi(v0.y);
    s1.x += bf_lo(v1.x); s1.y += bf_hi(v1.x); s1.z += bf_lo(v1.y); s1.w += bf_hi(v1.y);
    s2.x += bf_lo(v2.x); s2.y += bf_hi(v2.x); s2.z += bf_lo(v2.y); s2.w += bf_hi(v2.y);
    s3.x += bf_lo(v3.x); s3.y += bf_hi(v3.x); s3.z += bf_lo(v3.y); s3.w += bf_hi(v3.y);
    s4.x += bf_lo(v4.x); s4.y += bf_hi(v4.x); s4.z += bf_lo(v4.y); s4.w += bf_hi(v4.y);
    s5.x += bf_lo(v5.x); s5.y += bf_hi(v5.x); s5.z += bf_lo(v5.y); s5.w += bf_hi(v5.y);
  }
  float* ob = out + (size_t)g * ((N_LAYERS + 1) * D_HID) + t * 4;
  *reinterpret_cast<float4*>(ob + 0 * D_HID) = s0;
  *reinterpret_cast<float4*>(ob + 1 * D_HID) = s1;
  *reinterpret_cast<float4*>(ob + 2 * D_HID) = s2;
  *reinterpret_cast<float4*>(ob + 3 * D_HID) = s3;
  *reinterpret_cast<float4*>(ob + 4 * D_HID) = s4;
  *reinterpret_cast<float4*>(ob + 5 * D_HID) = s5;
}

// ---------------- launch ----------------

extern "C" void kernel_launch(void* const* d_in, const int* in_sizes, int n_in,
                              void* d_out, int out_size, void* d_ws, size_t ws_size,
                              hipStream_t stream) {
  const float* x       = (const float*)d_in[0];
  const int*   edges   = (const int*)d_in[1];
  const int*   src     = edges;
  const int*   dst     = edges + N_EDGES;
  const int*   batch   = (const int*)d_in[2];
  const float* W_embed = (const float*)d_in[3];
  const float* Ws      = (const float*)d_in[4];
  const float* bs      = (const float*)d_in[5];
  float* out = (float*)d_out;

  const size_t HSZ = (size_t)N_NODES * D_HID;
  unsigned short* hb[N_LAYERS + 1];
  hb[0] = (unsigned short*)d_ws;
  for (int l = 1; l <= N_LAYERS; ++l) hb[l] = hb[l - 1] + HSZ;
  unsigned short* wb_hi = hb[N_LAYERS] + HSZ;                 // 5*16384 bf16
  unsigned short* wb_lo = wb_hi + (size_t)N_LAYERS * 16384;   // 5*16384 bf16
  unsigned long long* aux = (unsigned long long*)(wb_lo + (size_t)N_LAYERS * 16384); // E u64
  int*   off    = (int*)(aux + N_EDGES);                      // N+1
  int*   bcount = off + (N_NODES + 1);                        // 256
  int*   bbase  = bcount + NBUCK;                             // 257
  int*   gcur   = bbase + (NBUCK + 1);                        // 256
  int*   csr    = gcur + NBUCK;                               // E
  int*   goff   = csr + N_EDGES;                              // G+1

  // bucketed CSR build (edge list is layer-invariant)
  zero_int_kernel<<<1, 256, 0, stream>>>(bcount, NBUCK);
  bucket_count_kernel<<<NCHUNKS, 256, 0, stream>>>(dst, bcount);
  bucket_scan_kernel<<<1, NBUCK, 0, stream>>>(bcount, bbase, gcur);
  bucket_scatter_kernel<<<NCHUNKS, 256, 0, stream>>>(src, dst, gcur, aux);
  bucket_csr_kernel<<<NBUCK, 256, 0, stream>>>(aux, bbase, off, csr);
  graph_off_kernel<<<(N_GRAPHS + 1 + 255) / 256, 256, 0, stream>>>(batch, goff);

  // W packing for MFMA
  pack_w_kernel<<<(N_LAYERS * 16384 + 255) / 256, 256, 0, stream>>>(Ws, wb_hi, wb_lo);

  // embedding
  embed_kernel<<<(N_NODES + 63) / 64, 256, 0, stream>>>(x, W_embed, hb[0]);

  // fused gather+gemm layers
  for (int l = 0; l < N_LAYERS; ++l) {
    gin_layer_kernel<<<N_NODES / 16, 256, 0, stream>>>(hb[l], off, csr,
                                                       wb_hi + (size_t)l * 16384,
                                                       wb_lo + (size_t)l * 16384,
                                                       bs + (size_t)l * D_HID, hb[l + 1]);
  }

  // single fused pool of all 6 features
  pool6_kernel<<<N_GRAPHS / 8, 256, 0, stream>>>(hb[0], hb[1], hb[2], hb[3], hb[4], hb[5],
                                                 goff, out);
}